// Round 1
// 154.655 us; speedup vs baseline: 1.4998x; 1.4998x over previous
//
#include <hip/hip_runtime.h>
#include <math.h>

#define NB 16
#define NA 8400
#define NG 50
#define TK 10
#define SELT 256
#define NCHUNK 33   // ceil(NA/256)
#define LCHUNK 16   // image-loss chunks per image

__device__ __forceinline__ float sigmoidf_(float x){ return 1.f/(1.f+expf(-x)); }
__device__ __forceinline__ float softplusf_(float x){ return log1pf(expf(-fabsf(x))) + fmaxf(x, 0.f); }
__device__ __forceinline__ float bce_(float x, float t){ return softplusf_(x) - x*t; }
__device__ __forceinline__ float sl1_(float d){
    const float B = 1.f/9.f;
    float a = fabsf(d);
    return a < B ? 0.5f*a*a/B : a - 0.5f*B;
}

__device__ __forceinline__ void anchor_geom(int a, int& lvl, int& hw, int& gx, int& gy, float& st){
    if (a < 6400){ lvl=0; hw=a;      gx=hw%80; gy=hw/80; st=8.f; }
    else if (a < 8000){ lvl=1; hw=a-6400; gx=hw%40; gy=hw/40; st=16.f; }
    else { lvl=2; hw=a-8000; gx=hw%20; gy=hw/20; st=32.f; }
}

// Single noinline emission => bit-identical cost at every call site.
// Only ever called for fg anchors (compacted list / matched anchors), so no fg term.
__device__ __attribute__((noinline)) float cost_fn(int a, float4 bx, float4 gb,
        int valid, int label, float ccPv, float ccNv, float* iou_out){
    int lvl, hw, gx, gy; float st;
    anchor_geom(a, lvl, hw, gx, gy, st);
    float ax = ((float)gx + 0.5f) * st, ay = ((float)gy + 0.5f) * st;
    float tlx = fmaxf(gb.x, bx.x), tly = fmaxf(gb.y, bx.y);
    float brx = fminf(gb.z, bx.z), bry = fminf(gb.w, bx.w);
    float iw = fmaxf(brx - tlx, 0.f), ih = fmaxf(bry - tly, 0.f);
    float inter = iw * ih;
    float ag = (gb.z - gb.x) * (gb.w - gb.y);
    float ab = (bx.z - bx.x) * (bx.w - bx.y);
    float im = inter / (ag + ab - inter + 1e-8f);
    *iou_out = im;
    float d1 = ax - gb.x, d2 = gb.z - ax, d3 = ay - gb.y, d4 = gb.w - ay;
    int inb = (fminf(fminf(d1,d2), fminf(d3,d4)) > 0.f) && valid;
    float cx = (gb.x + gb.z) * 0.5f, cy = (gb.y + gb.w) * 0.5f, r = 2.5f * st;
    float e1 = ax - (cx - r), e2 = (cx + r) - ax, e3 = ay - (cy - r), e4 = (cy + r) - ay;
    int inc = (fminf(fminf(e1,e2), fminf(e3,e4)) > 0.f) && valid;
    float c = ((label == 0) ? ccPv : ccNv) - 3.f * logf(im + 1e-8f);
    if (!(inb && inc)) c += 1e5f;
    if (!valid) c += 1e9f;
    return c;
}

__device__ __forceinline__ float giou_(float4 a, float4 b){
    float tlx = fmaxf(a.x,b.x), tly = fmaxf(a.y,b.y);
    float brx = fminf(a.z,b.z), bry = fminf(a.w,b.w);
    float iw = fmaxf(brx-tlx,0.f), ih = fmaxf(bry-tly,0.f);
    float inter = iw*ih;
    float aa = (a.z-a.x)*(a.w-a.y);
    float ab = (b.z-b.x)*(b.w-b.y);
    float uni = aa + ab - inter;
    float iou = inter / (uni + 1e-8f);
    float ctlx = fminf(a.x,b.x), ctly = fminf(a.y,b.y);
    float cbrx = fmaxf(a.z,b.z), cbry = fmaxf(a.w,b.w);
    float cw = fmaxf(cbrx-ctlx,0.f), ch = fmaxf(cbry-ctly,0.f);
    float ca = cw*ch;
    return iou - (ca - uni) / (ca + 1e-8f);
}

// ---------------- Kernel 0: parallel gt_valid normalize (byte vs int32 bool) + init ----------------
__global__ void k_init(const unsigned char* __restrict__ raw, unsigned char* __restrict__ v,
                       int* __restrict__ nFg){
    __shared__ int flag;
    if (threadIdx.x == 0) flag = 0;
    __syncthreads();
    int any = 0;
    // byte-layout iff any non-multiple-of-4 byte of the first 800 bytes is nonzero
    for (int i = threadIdx.x; i < NB*NG; i += blockDim.x){
        if ((i & 3) && raw[i]) any = 1;
    }
    if (any) flag = 1;           // benign race, all write 1
    __syncthreads();
    int isByte = flag;
    for (int i = threadIdx.x; i < NB*NG; i += blockDim.x){
        v[i] = isByte ? (raw[i] != 0) : (raw[4*i] != 0);
    }
    if (threadIdx.x < NB) nFg[threadIdx.x] = 0;
}

// ---------------- Kernel 1: decode + per-anchor precompute + fg compaction + match init ----------------
__global__ void __launch_bounds__(256) k_decode(
    const float* __restrict__ cls0, const float* __restrict__ reg0, const float* __restrict__ obj0, const float* __restrict__ lmk0,
    const float* __restrict__ cls1, const float* __restrict__ reg1, const float* __restrict__ obj1, const float* __restrict__ lmk1,
    const float* __restrict__ cls2, const float* __restrict__ reg2, const float* __restrict__ obj2, const float* __restrict__ lmk2,
    const float* __restrict__ gtb, const unsigned char* __restrict__ gtv,
    float4* __restrict__ boxes, float* __restrict__ objL, float* __restrict__ clsL,
    float* __restrict__ lmkD, float* __restrict__ ccP, float* __restrict__ ccN,
    int* __restrict__ fgList, int* __restrict__ nFg,
    int* __restrict__ mcnt, int* __restrict__ mfirst, float* __restrict__ mpiou)
{
    __shared__ float4 sgb[NG];
    __shared__ unsigned char sval[NG];
    int b = blockIdx.y;
    int tid = threadIdx.x;
    if (tid < NG){
        const float* gp = &gtb[(size_t)(b*NG+tid)*4];
        sgb[tid] = make_float4(gp[0], gp[1], gp[2], gp[3]);
        sval[tid] = gtv[b*NG+tid];
    }
    __syncthreads();

    int a = blockIdx.x * 256 + tid;
    if (a >= NA) return;
    int idx = b*NA + a;
    int lvl, hw, gx, gy; float st;
    anchor_geom(a, lvl, hw, gx, gy, st);
    const float* cp = lvl==0?cls0:(lvl==1?cls1:cls2);
    const float* rp = lvl==0?reg0:(lvl==1?reg1:reg2);
    const float* op = lvl==0?obj0:(lvl==1?obj1:obj2);
    const float* lp = lvl==0?lmk0:(lvl==1?lmk1:lmk2);
    int HW = lvl==0?6400:(lvl==1?1600:400);

    float rx = rp[(b*4+0)*HW+hw], ry = rp[(b*4+1)*HW+hw];
    float rw = rp[(b*4+2)*HW+hw], rh = rp[(b*4+3)*HW+hw];
    float xc = (rx + (float)gx) * st, yc = (ry + (float)gy) * st;
    float wd = expf(rw) * st, ht = expf(rh) * st;
    float4 bx = make_float4(xc - 0.5f*wd, yc - 0.5f*ht, xc + 0.5f*wd, yc + 0.5f*ht);
    boxes[idx] = bx;

    float cl = cp[b*HW+hw], ob = op[b*HW+hw];
    clsL[idx] = cl; objL[idx] = ob;
    float p = sqrtf(sigmoidf_(cl) * sigmoidf_(ob));
    ccP[idx] = -fmaxf(logf(p), -100.f);
    ccN[idx] = -fmaxf(logf(1.f - p), -100.f);

    #pragma unroll
    for (int k = 0; k < 5; k++){
        lmkD[idx*10 + 2*k]     = (lp[(b*10 + 2*k)*HW + hw]     + (float)gx) * st;
        lmkD[idx*10 + 2*k + 1] = (lp[(b*10 + 2*k + 1)*HW + hw] + (float)gy) * st;
    }

    // init per-anchor match state for k_select's scatter
    mcnt[idx] = 0; mfirst[idx] = 0x7fffffff; mpiou[idx] = 0.f;

    float ax = ((float)gx + 0.5f) * st, ay = ((float)gy + 0.5f) * st;
    float r = 2.5f * st;
    bool f = false;
    for (int g = 0; g < NG; g++){
        if (!sval[g]) continue;
        float4 gv = sgb[g];
        bool inb = fminf(fminf(ax-gv.x, gv.z-ax), fminf(ay-gv.y, gv.w-ay)) > 0.f;
        float cx = (gv.x+gv.z)*0.5f, cy = (gv.y+gv.w)*0.5f;
        bool inc = fminf(fminf(ax-(cx-r), (cx+r)-ax), fminf(ay-(cy-r), (cy+r)-ay)) > 0.f;
        f = f || inb || inc;
    }
    if (f){
        int pos = atomicAdd(&nFg[b], 1);
        fgList[b*NA + pos] = a;
    }
}

// ---------------- Kernel 2: per-(b,g) dyn_k top-k over COMPACTED fg anchors; scatter <=10 matches ----
// Matched set == first dk entries of the lex-(cost,idx)-sorted list (ties resolved by index,
// exactly the reference's stable-argsort rank < dyn_k). Non-fg anchors can never enter the
// lists: iou contribution 0, cost >= 1e9 > any fg cost (<= ~1e5+155).
__global__ void __launch_bounds__(SELT) k_select(
    const float4* __restrict__ boxes, const float* __restrict__ ccP, const float* __restrict__ ccN,
    const int* __restrict__ fgList, const int* __restrict__ nFg,
    const float* __restrict__ gtb, const int* __restrict__ gtl, const unsigned char* __restrict__ gtv,
    int* __restrict__ mcnt, int* __restrict__ mfirst, float* __restrict__ mpiou)
{
    int bg = blockIdx.x;
    int b = bg / NG, g = bg - b*NG;
    if (!gtv[b*NG+g]) return;      // uniform for the block; invalid GT matches nothing
    int tid = threadIdx.x;

    __shared__ float sIou[SELT*TK];
    __shared__ float sC[SELT*TK];
    __shared__ int   sI[SELT*TK];
    __shared__ int   sDk;

    const float* gp = &gtb[(size_t)(b*NG+g)*4];
    float4 gb = make_float4(gp[0], gp[1], gp[2], gp[3]);
    int label = gtl[b*NG+g];
    int nf = nFg[b];

    // register-resident top-k lists (static indices only)
    // iou sentinel 0.f == reference's zero rows for non-fg anchors (sum-safe if nf < TK)
    float mi[TK], mc[TK]; int mx[TK];
    #pragma unroll
    for (int k = 0; k < TK; k++){ mi[k] = 0.f; mc[k] = INFINITY; mx[k] = 0x7fffffff; }

    for (int i = tid; i < nf; i += SELT){
        int a = fgList[b*NA + i];
        int idx = b*NA + a;
        float im;
        float c = cost_fn(a, boxes[idx], gb, 1, label, ccP[idx], ccN[idx], &im);
        // bubble-insert iou (descending)
        float v = im;
        #pragma unroll
        for (int k = 0; k < TK; k++){
            if (v > mi[k]){ float t = mi[k]; mi[k] = v; v = t; }
        }
        // bubble-insert (cost, idx) lex ascending
        float cv = c; int iv = a;
        #pragma unroll
        for (int k = 0; k < TK; k++){
            bool lt = (cv < mc[k]) || (cv == mc[k] && iv < mx[k]);
            if (lt){
                float t = mc[k]; mc[k] = cv; cv = t;
                int ti = mx[k]; mx[k] = iv; iv = ti;
            }
        }
    }

    #pragma unroll
    for (int k = 0; k < TK; k++){
        sIou[tid*TK+k] = mi[k];
        sC[tid*TK+k] = mc[k];
        sI[tid*TK+k] = mx[k];
    }

    for (int off = SELT/2; off >= 1; off >>= 1){
        __syncthreads();
        if (tid < off){
            { // merge descending iou lists
                float* Al = &sIou[tid*TK]; float* Bl = &sIou[(tid+off)*TK];
                float r[TK]; int i = 0, j = 0;
                for (int k = 0; k < TK; k++){
                    bool ta = (j >= TK) || (i < TK && Al[i] >= Bl[j]);
                    r[k] = ta ? Al[i++] : Bl[j++];
                }
                for (int k = 0; k < TK; k++) Al[k] = r[k];
            }
            { // merge ascending lex (cost, idx) lists
                float* Ac = &sC[tid*TK]; int* Ai = &sI[tid*TK];
                float* Bc = &sC[(tid+off)*TK]; int* Bi = &sI[(tid+off)*TK];
                float rc[TK]; int ri[TK]; int i = 0, j = 0;
                for (int k = 0; k < TK; k++){
                    bool ta = (j >= TK) || (i < TK &&
                        (Ac[i] < Bc[j] || (Ac[i] == Bc[j] && Ai[i] <= Bi[j])));
                    if (ta){ rc[k] = Ac[i]; ri[k] = Ai[i]; i++; }
                    else   { rc[k] = Bc[j]; ri[k] = Bi[j]; j++; }
                }
                for (int k = 0; k < TK; k++){ Ac[k] = rc[k]; Ai[k] = ri[k]; }
            }
        }
    }
    __syncthreads();
    if (tid == 0){
        float s = 0.f;
        for (int k = 0; k < TK; k++) s += sIou[k];
        int dk = (int)s;
        if (dk < 1) dk = 1;
        if (dk > TK) dk = TK;
        sDk = dk;
    }
    __syncthreads();
    int dk = sDk;
    if (tid < dk){
        int a = sI[tid];
        if (a != 0x7fffffff){       // skip sentinels when nf < dk (=> all fg match, like ref)
            int idx = b*NA + a;
            atomicAdd(&mcnt[idx], 1);
            atomicMin(&mfirst[idx], g);
            float im;
            cost_fn(a, boxes[idx], gb, 1, label, ccP[idx], ccN[idx], &im);  // bit-identical re-eval
            atomicAdd(&mpiou[idx], im);   // single contributor when cnt==1 (only case it's read)
        }
    }
}

// ---------------- Kernel 3: per-image loss (conflict resolution folded in) ----------------
__global__ void __launch_bounds__(256) k_image_loss(
    const float4* __restrict__ boxes, const float* __restrict__ objL, const float* __restrict__ clsL,
    const float* __restrict__ lmkD, const float* __restrict__ ccP, const float* __restrict__ ccN,
    const int* __restrict__ mcnt, const int* __restrict__ mfirst, const float* __restrict__ mpiou,
    const float* __restrict__ gtb, const float* __restrict__ gtlm, const int* __restrict__ gtl,
    const unsigned char* __restrict__ gtv, double* __restrict__ partials)
{
    __shared__ float4 sgb[NG];
    __shared__ int slab[NG];
    __shared__ unsigned char sval[NG];
    __shared__ float slmk[NG*10];
    int b = blockIdx.y;
    int chunk = blockIdx.x;
    int tid = threadIdx.x;
    if (tid < NG){
        const float* gp = &gtb[(size_t)(b*NG+tid)*4];
        sgb[tid] = make_float4(gp[0], gp[1], gp[2], gp[3]);
        slab[tid] = gtl[b*NG+tid];
        sval[tid] = gtv[b*NG+tid];
    }
    for (int i = tid; i < NG*10; i += 256) slmk[i] = gtlm[(size_t)b*NG*10 + i];
    __syncthreads();

    const int CH = (NA + LCHUNK - 1) / LCHUNK;  // 525
    int a0 = chunk * CH;
    int a1 = min(a0 + CH, NA);
    double lo = 0, lc = 0, li = 0, lnum = 0, lden = 0, nfg = 0;

    for (int a = a0 + tid; a < a1; a += blockDim.x){
        int idx = b*NA + a;
        int cnt = mcnt[idx];
        float4 bx = boxes[idx];
        float f, pious; int m;
        if (cnt == 0){ f = 0.f; m = 0; pious = 0.f; }
        else if (cnt == 1){ f = 1.f; m = mfirst[idx]; pious = mpiou[idx]; }
        else {
            // conflict: argmin cost over ALL GTs (same as reference's keep=argmin)
            f = 1.f;
            float cp = ccP[idx], cn = ccN[idx];
            float bestC = INFINITY, bestIou = 0.f; int bestG = 0;
            for (int g = 0; g < NG; g++){
                float im;
                float c = cost_fn(a, bx, sgb[g], sval[g], slab[g], cp, cn, &im);
                if (c < bestC){ bestC = c; bestG = g; bestIou = im; }
            }
            m = bestG; pious = bestIou;
        }
        lo += (double)bce_(objL[idx], f);
        float tgt = (slab[m] == 0) ? pious : 0.f;
        lc += (double)(bce_(clsL[idx], tgt) * f);
        li += (double)((1.f - giou_(bx, sgb[m])) * f);
        if (cnt > 0){
            #pragma unroll
            for (int k = 0; k < 5; k++){
                float tx = slmk[m*10 + 2*k];
                float ty = slmk[m*10 + 2*k + 1];
                if (tx >= 0.f && ty >= 0.f){
                    lnum += (double)(sl1_(lmkD[idx*10 + 2*k] - tx) + sl1_(lmkD[idx*10 + 2*k + 1] - ty));
                    lden += 1.0;
                }
            }
        }
        nfg += (double)f;
    }

    __shared__ double s[6*256];
    s[0*256+tid] = lo; s[1*256+tid] = lc; s[2*256+tid] = li;
    s[3*256+tid] = lnum; s[4*256+tid] = lden; s[5*256+tid] = nfg;
    for (int off = 128; off >= 1; off >>= 1){
        __syncthreads();
        if (tid < off){
            #pragma unroll
            for (int q = 0; q < 6; q++) s[q*256+tid] += s[q*256+tid+off];
        }
    }
    if (tid == 0){
        #pragma unroll
        for (int q = 0; q < 6; q++) partials[(b*LCHUNK + chunk)*6 + q] = s[q*256];
    }
}

// ---------------- Kernel 4: final combine (parallel over images) ----------------
__global__ void k_final(const double* __restrict__ partials, float* __restrict__ out){
    __shared__ double s[NB][5];   // lo, lc, li, ll, nfg per image
    int t = threadIdx.x;
    if (t < NB){
        double lo = 0, lc = 0, li = 0, ln = 0, ld = 0, nf = 0;
        for (int ch = 0; ch < LCHUNK; ch++){
            const double* p = &partials[(t*LCHUNK + ch)*6];
            lo += p[0]; lc += p[1]; li += p[2];
            ln += p[3]; ld += p[4]; nf += p[5];
        }
        s[t][0] = lo; s[t][1] = lc; s[t][2] = li;
        s[t][3] = ln / fmax(ld, 1.0); s[t][4] = nf;
    }
    __syncthreads();
    if (t == 0){
        double lo = 0, lc = 0, li = 0, ll = 0, nfg = 0;
        for (int b = 0; b < NB; b++){
            lo += s[b][0]; lc += s[b][1]; li += s[b][2]; ll += s[b][3]; nfg += s[b][4];
        }
        double nf = fmax(nfg, 1.0);
        double liou = 5.0 * li / nf;
        double lobj = 1.0 * lo / nf;
        double lcls = 1.0 * lc / nf;
        double llmk = 5.0 * ll / nf;
        out[0] = (float)(liou + lobj + lcls + llmk);
        out[1] = (float)liou;
        out[2] = (float)lobj;
        out[3] = (float)lcls;
        out[4] = (float)llmk;
    }
}

extern "C" void kernel_launch(void* const* d_in, const int* in_sizes, int n_in,
                              void* d_out, int out_size, void* d_ws, size_t ws_size,
                              hipStream_t stream) {
    const float* cls0 = (const float*)d_in[0];
    const float* reg0 = (const float*)d_in[1];
    const float* obj0 = (const float*)d_in[2];
    const float* lmk0 = (const float*)d_in[3];
    const float* cls1 = (const float*)d_in[4];
    const float* reg1 = (const float*)d_in[5];
    const float* obj1 = (const float*)d_in[6];
    const float* lmk1 = (const float*)d_in[7];
    const float* cls2 = (const float*)d_in[8];
    const float* reg2 = (const float*)d_in[9];
    const float* obj2 = (const float*)d_in[10];
    const float* lmk2 = (const float*)d_in[11];
    const float* gtb  = (const float*)d_in[12];
    const float* gtlm = (const float*)d_in[13];
    const int*   gtl  = (const int*)d_in[14];
    const unsigned char* gtv_raw = (const unsigned char*)d_in[15];
    float* out = (float*)d_out;

    char* ws = (char*)d_ws;
    size_t off = 0;
    float4* boxes = (float4*)(ws + off); off += (size_t)NB*NA*sizeof(float4);
    float* lmkD = (float*)(ws + off); off += (size_t)NB*NA*10*sizeof(float);
    float* objL = (float*)(ws + off); off += (size_t)NB*NA*sizeof(float);
    float* clsL = (float*)(ws + off); off += (size_t)NB*NA*sizeof(float);
    float* ccP  = (float*)(ws + off); off += (size_t)NB*NA*sizeof(float);
    float* ccN  = (float*)(ws + off); off += (size_t)NB*NA*sizeof(float);
    float* mpiou = (float*)(ws + off); off += (size_t)NB*NA*sizeof(float);
    int* mcnt   = (int*)(ws + off);   off += (size_t)NB*NA*sizeof(int);
    int* mfirst = (int*)(ws + off);   off += (size_t)NB*NA*sizeof(int);
    int* fgList = (int*)(ws + off);   off += (size_t)NB*NA*sizeof(int);
    int* nFg    = (int*)(ws + off);   off += (size_t)64;
    double* partials = (double*)(ws + off); off += (size_t)NB*LCHUNK*6*sizeof(double);
    unsigned char* gtv = (unsigned char*)(ws + off); off += (size_t)NB*NG;

    k_init<<<dim3(1), dim3(256), 0, stream>>>(gtv_raw, gtv, nFg);

    dim3 grdA(NCHUNK, NB);
    k_decode<<<grdA, dim3(256), 0, stream>>>(cls0, reg0, obj0, lmk0, cls1, reg1, obj1, lmk1,
                                             cls2, reg2, obj2, lmk2, gtb, gtv,
                                             boxes, objL, clsL, lmkD, ccP, ccN,
                                             fgList, nFg, mcnt, mfirst, mpiou);

    k_select<<<dim3(NB*NG), dim3(SELT), 0, stream>>>(boxes, ccP, ccN, fgList, nFg,
                                                     gtb, gtl, gtv, mcnt, mfirst, mpiou);

    k_image_loss<<<dim3(LCHUNK, NB), dim3(256), 0, stream>>>(boxes, objL, clsL, lmkD, ccP, ccN,
                                                             mcnt, mfirst, mpiou,
                                                             gtb, gtlm, gtl, gtv, partials);

    k_final<<<dim3(1), dim3(64), 0, stream>>>(partials, out);
}

// Round 2
// 131.590 us; speedup vs baseline: 1.7627x; 1.1753x over previous
//
#include <hip/hip_runtime.h>
#include <math.h>

#define NB 16
#define NA 8400
#define NG 50
#define TK 10
#define SELT 256
#define NCHUNK 33   // ceil(NA/256)
#define FGB 2       // fg-loss blocks per image (2*256 >= TK*NG=500 max matched)
#define MCAP 512    // matched-list capacity per image

__device__ __forceinline__ float sigmoidf_(float x){ return 1.f/(1.f+expf(-x)); }
__device__ __forceinline__ float softplusf_(float x){ return log1pf(expf(-fabsf(x))) + fmaxf(x, 0.f); }
__device__ __forceinline__ float bce_(float x, float t){ return softplusf_(x) - x*t; }
__device__ __forceinline__ float sl1_(float d){
    const float B = 1.f/9.f;
    float a = fabsf(d);
    return a < B ? 0.5f*a*a/B : a - 0.5f*B;
}

__device__ __forceinline__ void anchor_geom(int a, int& lvl, int& hw, int& gx, int& gy, float& st){
    if (a < 6400){ lvl=0; hw=a;      gx=hw%80; gy=hw/80; st=8.f; }
    else if (a < 8000){ lvl=1; hw=a-6400; gx=hw%40; gy=hw/40; st=16.f; }
    else { lvl=2; hw=a-8000; gx=hw%20; gy=hw/20; st=32.f; }
}

// Single noinline emission per module => bit-identical cost at every call site in every kernel.
// Only ever called for fg anchors, so no fg term.
__device__ __attribute__((noinline)) float cost_fn(int a, float4 bx, float4 gb,
        int valid, int label, float ccPv, float ccNv, float* iou_out){
    int lvl, hw, gx, gy; float st;
    anchor_geom(a, lvl, hw, gx, gy, st);
    float ax = ((float)gx + 0.5f) * st, ay = ((float)gy + 0.5f) * st;
    float tlx = fmaxf(gb.x, bx.x), tly = fmaxf(gb.y, bx.y);
    float brx = fminf(gb.z, bx.z), bry = fminf(gb.w, bx.w);
    float iw = fmaxf(brx - tlx, 0.f), ih = fmaxf(bry - tly, 0.f);
    float inter = iw * ih;
    float ag = (gb.z - gb.x) * (gb.w - gb.y);
    float ab = (bx.z - bx.x) * (bx.w - bx.y);
    float im = inter / (ag + ab - inter + 1e-8f);
    *iou_out = im;
    float d1 = ax - gb.x, d2 = gb.z - ax, d3 = ay - gb.y, d4 = gb.w - ay;
    int inb = (fminf(fminf(d1,d2), fminf(d3,d4)) > 0.f) && valid;
    float cx = (gb.x + gb.z) * 0.5f, cy = (gb.y + gb.w) * 0.5f, r = 2.5f * st;
    float e1 = ax - (cx - r), e2 = (cx + r) - ax, e3 = ay - (cy - r), e4 = (cy + r) - ay;
    int inc = (fminf(fminf(e1,e2), fminf(e3,e4)) > 0.f) && valid;
    float c = ((label == 0) ? ccPv : ccNv) - 3.f * logf(im + 1e-8f);
    if (!(inb && inc)) c += 1e5f;
    if (!valid) c += 1e9f;
    return c;
}

__device__ __forceinline__ float giou_(float4 a, float4 b){
    float tlx = fmaxf(a.x,b.x), tly = fmaxf(a.y,b.y);
    float brx = fminf(a.z,b.z), bry = fminf(a.w,b.w);
    float iw = fmaxf(brx-tlx,0.f), ih = fmaxf(bry-tly,0.f);
    float inter = iw*ih;
    float aa = (a.z-a.x)*(a.w-a.y);
    float ab = (b.z-b.x)*(b.w-b.y);
    float uni = aa + ab - inter;
    float iou = inter / (uni + 1e-8f);
    float ctlx = fminf(a.x,b.x), ctly = fminf(a.y,b.y);
    float cbrx = fmaxf(a.z,b.z), cbry = fmaxf(a.w,b.w);
    float cw = fmaxf(cbrx-ctlx,0.f), ch = fmaxf(cbry-ctly,0.f);
    float ca = cw*ch;
    return iou - (ca - uni) / (ca + 1e-8f);
}

// ---------------- Kernel 0: parallel gt_valid normalize (byte vs int32 bool) + counters init ----
__global__ void k_init(const unsigned char* __restrict__ raw, unsigned char* __restrict__ v,
                       int* __restrict__ nFg, int* __restrict__ nM){
    __shared__ int flag;
    if (threadIdx.x == 0) flag = 0;
    __syncthreads();
    int any = 0;
    for (int i = threadIdx.x; i < NB*NG; i += blockDim.x){
        if ((i & 3) && raw[i]) any = 1;
    }
    if (any) flag = 1;           // benign race, all write 1
    __syncthreads();
    int isByte = flag;
    for (int i = threadIdx.x; i < NB*NG; i += blockDim.x){
        v[i] = isByte ? (raw[i] != 0) : (raw[4*i] != 0);
    }
    if (threadIdx.x < NB){ nFg[threadIdx.x] = 0; nM[threadIdx.x] = 0; }
}

// ---------------- Kernel 1: decode + precompute + dense obj-loss + ordered fg compaction --------
__global__ void __launch_bounds__(256) k_decode(
    const float* __restrict__ cls0, const float* __restrict__ reg0, const float* __restrict__ obj0, const float* __restrict__ lmk0,
    const float* __restrict__ cls1, const float* __restrict__ reg1, const float* __restrict__ obj1, const float* __restrict__ lmk1,
    const float* __restrict__ cls2, const float* __restrict__ reg2, const float* __restrict__ obj2, const float* __restrict__ lmk2,
    const float* __restrict__ gtb, const unsigned char* __restrict__ gtv,
    float4* __restrict__ boxes, float* __restrict__ objL, float* __restrict__ clsL,
    float* __restrict__ lmkD, float* __restrict__ ccP, float* __restrict__ ccN,
    int* __restrict__ fgList, int* __restrict__ nFg,
    int* __restrict__ mcnt, int* __restrict__ mfirst, float* __restrict__ mpiou,
    double* __restrict__ pObj)
{
    __shared__ float4 sgb[NG];
    __shared__ unsigned char sval[NG];
    __shared__ double sred[256];
    int b = blockIdx.y;
    int tid = threadIdx.x;
    if (tid < NG){
        const float* gp = &gtb[(size_t)(b*NG+tid)*4];
        sgb[tid] = make_float4(gp[0], gp[1], gp[2], gp[3]);
        sval[tid] = gtv[b*NG+tid];
    }
    __syncthreads();

    int a = blockIdx.x * 256 + tid;
    bool act = (a < NA);
    double so = 0.0;
    bool f = false;
    if (act){
        int idx = b*NA + a;
        int lvl, hw, gx, gy; float st;
        anchor_geom(a, lvl, hw, gx, gy, st);
        const float* cp = lvl==0?cls0:(lvl==1?cls1:cls2);
        const float* rp = lvl==0?reg0:(lvl==1?reg1:reg2);
        const float* op = lvl==0?obj0:(lvl==1?obj1:obj2);
        const float* lp = lvl==0?lmk0:(lvl==1?lmk1:lmk2);
        int HW = lvl==0?6400:(lvl==1?1600:400);

        float rx = rp[(b*4+0)*HW+hw], ry = rp[(b*4+1)*HW+hw];
        float rw = rp[(b*4+2)*HW+hw], rh = rp[(b*4+3)*HW+hw];
        float xc = (rx + (float)gx) * st, yc = (ry + (float)gy) * st;
        float wd = expf(rw) * st, ht = expf(rh) * st;
        float4 bx = make_float4(xc - 0.5f*wd, yc - 0.5f*ht, xc + 0.5f*wd, yc + 0.5f*ht);
        boxes[idx] = bx;

        float cl = cp[b*HW+hw], ob = op[b*HW+hw];
        clsL[idx] = cl; objL[idx] = ob;
        so = (double)softplusf_(ob);     // dense obj-loss term: bce(x,0) = softplus(x)
        float p = sqrtf(sigmoidf_(cl) * sigmoidf_(ob));
        ccP[idx] = -fmaxf(logf(p), -100.f);
        ccN[idx] = -fmaxf(logf(1.f - p), -100.f);

        #pragma unroll
        for (int k = 0; k < 5; k++){
            lmkD[idx*10 + 2*k]     = (lp[(b*10 + 2*k)*HW + hw]     + (float)gx) * st;
            lmkD[idx*10 + 2*k + 1] = (lp[(b*10 + 2*k + 1)*HW + hw] + (float)gy) * st;
        }

        mcnt[idx] = 0; mfirst[idx] = 0x7fffffff; mpiou[idx] = 0.f;

        float ax = ((float)gx + 0.5f) * st, ay = ((float)gy + 0.5f) * st;
        float r = 2.5f * st;
        for (int g = 0; g < NG; g++){
            if (!sval[g]) continue;
            float4 gv = sgb[g];
            bool inb = fminf(fminf(ax-gv.x, gv.z-ax), fminf(ay-gv.y, gv.w-ay)) > 0.f;
            float cx = (gv.x+gv.z)*0.5f, cy = (gv.y+gv.w)*0.5f;
            bool inc = fminf(fminf(ax-(cx-r), (cx+r)-ax), fminf(ay-(cy-r), (cy+r)-ay)) > 0.f;
            f = f || inb || inc;
        }
    }

    // wave-ballot ordered append: consecutive fg anchors land contiguously in fgList
    unsigned long long m = __ballot(f);
    int lane = tid & 63;
    if (m){
        int ld = __ffsll(m) - 1;
        int base = 0;
        if (lane == ld) base = atomicAdd(&nFg[b], __popcll(m));
        base = __shfl(base, ld);
        if (f){
            int pos = base + __popcll(m & ((1ull << lane) - 1ull));
            fgList[b*NA + pos] = a;
        }
    }

    // block reduction of dense obj loss (no extra global loads)
    sred[tid] = so;
    for (int off = 128; off >= 1; off >>= 1){
        __syncthreads();
        if (tid < off) sred[tid] += sred[tid+off];
    }
    if (tid == 0) pObj[b*NCHUNK + blockIdx.x] = sred[0];
}

// ---------------- Kernel 2: per-(b,g) dyn_k top-k over compacted fg anchors; scatter matches ----
__global__ void __launch_bounds__(SELT) k_select(
    const float4* __restrict__ boxes, const float* __restrict__ ccP, const float* __restrict__ ccN,
    const int* __restrict__ fgList, const int* __restrict__ nFg,
    const float* __restrict__ gtb, const int* __restrict__ gtl, const unsigned char* __restrict__ gtv,
    int* __restrict__ mcnt, int* __restrict__ mfirst, float* __restrict__ mpiou,
    int* __restrict__ mList, int* __restrict__ nM)
{
    int bg = blockIdx.x;
    int b = bg / NG, g = bg - b*NG;
    if (!gtv[b*NG+g]) return;      // uniform for the block; invalid GT matches nothing
    int tid = threadIdx.x;

    __shared__ float sIou[SELT*TK];
    __shared__ float sC[SELT*TK];
    __shared__ int   sI[SELT*TK];
    __shared__ int   sDk;

    const float* gp = &gtb[(size_t)(b*NG+g)*4];
    float4 gb = make_float4(gp[0], gp[1], gp[2], gp[3]);
    int label = gtl[b*NG+g];
    int nf = nFg[b];

    // iou sentinel 0.f == reference's zero rows (sum-safe when nf < TK)
    float mi[TK], mc[TK]; int mx[TK];
    #pragma unroll
    for (int k = 0; k < TK; k++){ mi[k] = 0.f; mc[k] = INFINITY; mx[k] = 0x7fffffff; }

    for (int i = tid; i < nf; i += SELT){
        int a = fgList[b*NA + i];
        int idx = b*NA + a;
        float im;
        float c = cost_fn(a, boxes[idx], gb, 1, label, ccP[idx], ccN[idx], &im);
        float v = im;
        #pragma unroll
        for (int k = 0; k < TK; k++){
            if (v > mi[k]){ float t = mi[k]; mi[k] = v; v = t; }
        }
        float cv = c; int iv = a;
        #pragma unroll
        for (int k = 0; k < TK; k++){
            bool lt = (cv < mc[k]) || (cv == mc[k] && iv < mx[k]);
            if (lt){
                float t = mc[k]; mc[k] = cv; cv = t;
                int ti = mx[k]; mx[k] = iv; iv = ti;
            }
        }
    }

    #pragma unroll
    for (int k = 0; k < TK; k++){
        sIou[tid*TK+k] = mi[k];
        sC[tid*TK+k] = mc[k];
        sI[tid*TK+k] = mx[k];
    }

    for (int off = SELT/2; off >= 1; off >>= 1){
        __syncthreads();
        if (tid < off){
            { // merge descending iou lists
                float* Al = &sIou[tid*TK]; float* Bl = &sIou[(tid+off)*TK];
                float r[TK]; int i = 0, j = 0;
                for (int k = 0; k < TK; k++){
                    bool ta = (j >= TK) || (i < TK && Al[i] >= Bl[j]);
                    r[k] = ta ? Al[i++] : Bl[j++];
                }
                for (int k = 0; k < TK; k++) Al[k] = r[k];
            }
            { // merge ascending lex (cost, idx) lists
                float* Ac = &sC[tid*TK]; int* Ai = &sI[tid*TK];
                float* Bc = &sC[(tid+off)*TK]; int* Bi = &sI[(tid+off)*TK];
                float rc[TK]; int ri[TK]; int i = 0, j = 0;
                for (int k = 0; k < TK; k++){
                    bool ta = (j >= TK) || (i < TK &&
                        (Ac[i] < Bc[j] || (Ac[i] == Bc[j] && Ai[i] <= Bi[j])));
                    if (ta){ rc[k] = Ac[i]; ri[k] = Ai[i]; i++; }
                    else   { rc[k] = Bc[j]; ri[k] = Bi[j]; j++; }
                }
                for (int k = 0; k < TK; k++){ Ac[k] = rc[k]; Ai[k] = ri[k]; }
            }
        }
    }
    __syncthreads();
    if (tid == 0){
        float s = 0.f;
        for (int k = 0; k < TK; k++) s += sIou[k];
        int dk = (int)s;
        if (dk < 1) dk = 1;
        if (dk > TK) dk = TK;
        sDk = dk;
    }
    __syncthreads();
    int dk = sDk;
    if (tid < dk){
        int a = sI[tid];
        if (a != 0x7fffffff){       // skip sentinels when nf < dk
            int idx = b*NA + a;
            int old = atomicAdd(&mcnt[idx], 1);
            if (old == 0){          // first match appends anchor to compact matched list
                int p = atomicAdd(&nM[b], 1);
                mList[b*MCAP + p] = a;
            }
            atomicMin(&mfirst[idx], g);
            float im;
            cost_fn(a, boxes[idx], gb, 1, label, ccP[idx], ccN[idx], &im);  // bit-identical re-eval
            atomicAdd(&mpiou[idx], im);   // single contributor when cnt==1 (only case it's read)
        }
    }
}

// ---------------- Kernel 3: fg-only losses over compacted matched anchors ----------------------
__global__ void __launch_bounds__(256) k_fg_loss(
    const float4* __restrict__ boxes, const float* __restrict__ objL, const float* __restrict__ clsL,
    const float* __restrict__ lmkD, const float* __restrict__ ccP, const float* __restrict__ ccN,
    const int* __restrict__ mcnt, const int* __restrict__ mfirst, const float* __restrict__ mpiou,
    const int* __restrict__ mList, const int* __restrict__ nM,
    const float* __restrict__ gtb, const float* __restrict__ gtlm, const int* __restrict__ gtl,
    const unsigned char* __restrict__ gtv, double* __restrict__ partials)
{
    __shared__ float4 sgb[NG];
    __shared__ int slab[NG];
    __shared__ unsigned char sval[NG];
    __shared__ float slmk[NG*10];
    int b = blockIdx.y;
    int tid = threadIdx.x;
    if (tid < NG){
        const float* gp = &gtb[(size_t)(b*NG+tid)*4];
        sgb[tid] = make_float4(gp[0], gp[1], gp[2], gp[3]);
        slab[tid] = gtl[b*NG+tid];
        sval[tid] = gtv[b*NG+tid];
    }
    for (int i = tid; i < NG*10; i += 256) slmk[i] = gtlm[(size_t)b*NG*10 + i];
    __syncthreads();

    int n = nM[b];
    double lo = 0, lc = 0, li = 0, lnum = 0, lden = 0, nfg = 0;

    for (int i = blockIdx.x*256 + tid; i < n; i += FGB*256){
        int a = mList[b*MCAP + i];
        int idx = b*NA + a;
        int cnt = mcnt[idx];
        float4 bx = boxes[idx];
        float pious; int m;
        if (cnt == 1){ m = mfirst[idx]; pious = mpiou[idx]; }
        else {
            // conflict: argmin cost over ALL GTs (reference's keep = argmin, first-min on ties)
            float cp = ccP[idx], cn = ccN[idx];
            float bestC = INFINITY, bestIou = 0.f; int bestG = 0;
            for (int g = 0; g < NG; g++){
                float im;
                float c = cost_fn(a, bx, sgb[g], sval[g], slab[g], cp, cn, &im);
                if (c < bestC){ bestC = c; bestG = g; bestIou = im; }
            }
            m = bestG; pious = bestIou;
        }
        lo += (double)(-objL[idx]);              // bce(x,1) - bce(x,0) = -x  (fg correction)
        float tgt = (slab[m] == 0) ? pious : 0.f;
        lc += (double)bce_(clsL[idx], tgt);
        li += (double)(1.f - giou_(bx, sgb[m]));
        #pragma unroll
        for (int k = 0; k < 5; k++){
            float tx = slmk[m*10 + 2*k];
            float ty = slmk[m*10 + 2*k + 1];
            if (tx >= 0.f && ty >= 0.f){
                lnum += (double)(sl1_(lmkD[idx*10 + 2*k] - tx) + sl1_(lmkD[idx*10 + 2*k + 1] - ty));
                lden += 1.0;
            }
        }
        nfg += 1.0;
    }

    __shared__ double s[6*256];
    s[0*256+tid] = lo; s[1*256+tid] = lc; s[2*256+tid] = li;
    s[3*256+tid] = lnum; s[4*256+tid] = lden; s[5*256+tid] = nfg;
    for (int off = 128; off >= 1; off >>= 1){
        __syncthreads();
        if (tid < off){
            #pragma unroll
            for (int q = 0; q < 6; q++) s[q*256+tid] += s[q*256+tid+off];
        }
    }
    if (tid == 0){
        #pragma unroll
        for (int q = 0; q < 6; q++) partials[(b*FGB + blockIdx.x)*6 + q] = s[q*256];
    }
}

// ---------------- Kernel 4: final combine (parallel over images) ----------------
__global__ void k_final(const double* __restrict__ pObj, const double* __restrict__ partials,
                        float* __restrict__ out){
    __shared__ double s[NB][5];   // lo, lc, li, ll, nfg per image
    int t = threadIdx.x;
    if (t < NB){
        double lo = 0, lc = 0, li = 0, ln = 0, ld = 0, nf = 0;
        for (int ch = 0; ch < NCHUNK; ch++) lo += pObj[t*NCHUNK + ch];
        for (int blk = 0; blk < FGB; blk++){
            const double* p = &partials[(t*FGB + blk)*6];
            lo += p[0]; lc += p[1]; li += p[2];
            ln += p[3]; ld += p[4]; nf += p[5];
        }
        s[t][0] = lo; s[t][1] = lc; s[t][2] = li;
        s[t][3] = ln / fmax(ld, 1.0); s[t][4] = nf;
    }
    __syncthreads();
    if (t == 0){
        double lo = 0, lc = 0, li = 0, ll = 0, nfg = 0;
        for (int b = 0; b < NB; b++){
            lo += s[b][0]; lc += s[b][1]; li += s[b][2]; ll += s[b][3]; nfg += s[b][4];
        }
        double nf = fmax(nfg, 1.0);
        double liou = 5.0 * li / nf;
        double lobj = 1.0 * lo / nf;
        double lcls = 1.0 * lc / nf;
        double llmk = 5.0 * ll / nf;
        out[0] = (float)(liou + lobj + lcls + llmk);
        out[1] = (float)liou;
        out[2] = (float)lobj;
        out[3] = (float)lcls;
        out[4] = (float)llmk;
    }
}

extern "C" void kernel_launch(void* const* d_in, const int* in_sizes, int n_in,
                              void* d_out, int out_size, void* d_ws, size_t ws_size,
                              hipStream_t stream) {
    const float* cls0 = (const float*)d_in[0];
    const float* reg0 = (const float*)d_in[1];
    const float* obj0 = (const float*)d_in[2];
    const float* lmk0 = (const float*)d_in[3];
    const float* cls1 = (const float*)d_in[4];
    const float* reg1 = (const float*)d_in[5];
    const float* obj1 = (const float*)d_in[6];
    const float* lmk1 = (const float*)d_in[7];
    const float* cls2 = (const float*)d_in[8];
    const float* reg2 = (const float*)d_in[9];
    const float* obj2 = (const float*)d_in[10];
    const float* lmk2 = (const float*)d_in[11];
    const float* gtb  = (const float*)d_in[12];
    const float* gtlm = (const float*)d_in[13];
    const int*   gtl  = (const int*)d_in[14];
    const unsigned char* gtv_raw = (const unsigned char*)d_in[15];
    float* out = (float*)d_out;

    char* ws = (char*)d_ws;
    size_t off = 0;
    float4* boxes = (float4*)(ws + off); off += (size_t)NB*NA*sizeof(float4);
    float* lmkD = (float*)(ws + off); off += (size_t)NB*NA*10*sizeof(float);
    float* objL = (float*)(ws + off); off += (size_t)NB*NA*sizeof(float);
    float* clsL = (float*)(ws + off); off += (size_t)NB*NA*sizeof(float);
    float* ccP  = (float*)(ws + off); off += (size_t)NB*NA*sizeof(float);
    float* ccN  = (float*)(ws + off); off += (size_t)NB*NA*sizeof(float);
    float* mpiou = (float*)(ws + off); off += (size_t)NB*NA*sizeof(float);
    int* mcnt   = (int*)(ws + off);   off += (size_t)NB*NA*sizeof(int);
    int* mfirst = (int*)(ws + off);   off += (size_t)NB*NA*sizeof(int);
    int* fgList = (int*)(ws + off);   off += (size_t)NB*NA*sizeof(int);
    int* mList  = (int*)(ws + off);   off += (size_t)NB*MCAP*sizeof(int);
    int* nFg    = (int*)(ws + off);   off += (size_t)64;
    int* nM     = (int*)(ws + off);   off += (size_t)64;
    double* pObj = (double*)(ws + off); off += (size_t)NB*NCHUNK*sizeof(double);
    double* partials = (double*)(ws + off); off += (size_t)NB*FGB*6*sizeof(double);
    unsigned char* gtv = (unsigned char*)(ws + off); off += (size_t)NB*NG;

    k_init<<<dim3(1), dim3(256), 0, stream>>>(gtv_raw, gtv, nFg, nM);

    dim3 grdA(NCHUNK, NB);
    k_decode<<<grdA, dim3(256), 0, stream>>>(cls0, reg0, obj0, lmk0, cls1, reg1, obj1, lmk1,
                                             cls2, reg2, obj2, lmk2, gtb, gtv,
                                             boxes, objL, clsL, lmkD, ccP, ccN,
                                             fgList, nFg, mcnt, mfirst, mpiou, pObj);

    k_select<<<dim3(NB*NG), dim3(SELT), 0, stream>>>(boxes, ccP, ccN, fgList, nFg,
                                                     gtb, gtl, gtv, mcnt, mfirst, mpiou,
                                                     mList, nM);

    k_fg_loss<<<dim3(FGB, NB), dim3(256), 0, stream>>>(boxes, objL, clsL, lmkD, ccP, ccN,
                                                       mcnt, mfirst, mpiou, mList, nM,
                                                       gtb, gtlm, gtl, gtv, partials);

    k_final<<<dim3(1), dim3(64), 0, stream>>>(pObj, partials, out);
}

// Round 3
// 111.737 us; speedup vs baseline: 2.0759x; 1.1777x over previous
//
#include <hip/hip_runtime.h>
#include <math.h>

#define NB 16
#define NA 8400
#define NG 50
#define TK 10
#define SELT 256
#define NCHUNK 33   // ceil(NA/256)
#define FGB 2       // fg-loss blocks per image (2*256 >= TK*NG=500 max matched)
#define MCAP 512    // matched-list capacity per image

__device__ __forceinline__ float sigmoidf_(float x){ return 1.f/(1.f+expf(-x)); }
__device__ __forceinline__ float softplusf_(float x){ return log1pf(expf(-fabsf(x))) + fmaxf(x, 0.f); }
__device__ __forceinline__ float bce_(float x, float t){ return softplusf_(x) - x*t; }
__device__ __forceinline__ float sl1_(float d){
    const float B = 1.f/9.f;
    float a = fabsf(d);
    return a < B ? 0.5f*a*a/B : a - 0.5f*B;
}

__device__ __forceinline__ void anchor_geom(int a, int& lvl, int& hw, int& gx, int& gy, float& st){
    if (a < 6400){ lvl=0; hw=a;      gx=hw%80; gy=hw/80; st=8.f; }
    else if (a < 8000){ lvl=1; hw=a-6400; gx=hw%40; gy=hw/40; st=16.f; }
    else { lvl=2; hw=a-8000; gx=hw%20; gy=hw/20; st=32.f; }
}

__device__ __forceinline__ float giou_(float4 a, float4 b){
    float tlx = fmaxf(a.x,b.x), tly = fmaxf(a.y,b.y);
    float brx = fminf(a.z,b.z), bry = fminf(a.w,b.w);
    float iw = fmaxf(brx-tlx,0.f), ih = fmaxf(bry-tly,0.f);
    float inter = iw*ih;
    float aa = (a.z-a.x)*(a.w-a.y);
    float ab = (b.z-b.x)*(b.w-b.y);
    float uni = aa + ab - inter;
    float iou = inter / (uni + 1e-8f);
    float ctlx = fminf(a.x,b.x), ctly = fminf(a.y,b.y);
    float cbrx = fmaxf(a.z,b.z), cbry = fmaxf(a.w,b.w);
    float cw = fmaxf(cbrx-ctlx,0.f), ch = fmaxf(cbry-ctly,0.f);
    float ca = cw*ch;
    return iou - (ca - uni) / (ca + 1e-8f);
}

// ---------------- Kernel 0: parallel gt_valid normalize (byte vs int32 bool) + counters init ----
__global__ void k_init(const unsigned char* __restrict__ raw, unsigned char* __restrict__ v,
                       int* __restrict__ nFg, int* __restrict__ nM, int* __restrict__ done){
    __shared__ int flag;
    if (threadIdx.x == 0) flag = 0;
    __syncthreads();
    int any = 0;
    for (int i = threadIdx.x; i < NB*NG; i += blockDim.x){
        if ((i & 3) && raw[i]) any = 1;
    }
    if (any) flag = 1;           // benign race, all write 1
    __syncthreads();
    int isByte = flag;
    for (int i = threadIdx.x; i < NB*NG; i += blockDim.x){
        v[i] = isByte ? (raw[i] != 0) : (raw[4*i] != 0);
    }
    if (threadIdx.x < NB){ nFg[threadIdx.x] = 0; nM[threadIdx.x] = 0; }
    if (threadIdx.x == 0) done[0] = 0;
}

// ---------------- Kernel 1: decode + precompute + dense obj-loss + ordered fg compaction --------
// Writes compacted AoS (boxC/metaC/ccNC) at append time so k_select streams coalesced data.
__global__ void __launch_bounds__(256) k_decode(
    const float* __restrict__ cls0, const float* __restrict__ reg0, const float* __restrict__ obj0, const float* __restrict__ lmk0,
    const float* __restrict__ cls1, const float* __restrict__ reg1, const float* __restrict__ obj1, const float* __restrict__ lmk1,
    const float* __restrict__ cls2, const float* __restrict__ reg2, const float* __restrict__ obj2, const float* __restrict__ lmk2,
    const float* __restrict__ gtb, const unsigned char* __restrict__ gtv,
    float4* __restrict__ boxes, float* __restrict__ objL, float* __restrict__ clsL,
    float* __restrict__ lmkD, float* __restrict__ ccP, float* __restrict__ ccN,
    int* __restrict__ fgList, int* __restrict__ nFg,
    float4* __restrict__ boxC, float4* __restrict__ metaC, float* __restrict__ ccNC,
    int* __restrict__ mcnt, int* __restrict__ mfirst, float* __restrict__ mpiou,
    double* __restrict__ pObj)
{
    __shared__ float4 sgb[NG];
    __shared__ unsigned char sval[NG];
    __shared__ double sred[256];
    int b = blockIdx.y;
    int tid = threadIdx.x;
    if (tid < NG){
        const float* gp = &gtb[(size_t)(b*NG+tid)*4];
        sgb[tid] = make_float4(gp[0], gp[1], gp[2], gp[3]);
        sval[tid] = gtv[b*NG+tid];
    }
    __syncthreads();

    int a = blockIdx.x * 256 + tid;
    bool act = (a < NA);
    double so = 0.0;
    bool f = false;
    float4 bx; float ax = 0.f, ay = 0.f, r = 0.f, ccPv = 0.f, ccNv = 0.f;
    if (act){
        int idx = b*NA + a;
        int lvl, hw, gx, gy; float st;
        anchor_geom(a, lvl, hw, gx, gy, st);
        const float* cp = lvl==0?cls0:(lvl==1?cls1:cls2);
        const float* rp = lvl==0?reg0:(lvl==1?reg1:reg2);
        const float* op = lvl==0?obj0:(lvl==1?obj1:obj2);
        const float* lp = lvl==0?lmk0:(lvl==1?lmk1:lmk2);
        int HW = lvl==0?6400:(lvl==1?1600:400);

        float rx = rp[(b*4+0)*HW+hw], ry = rp[(b*4+1)*HW+hw];
        float rw = rp[(b*4+2)*HW+hw], rh = rp[(b*4+3)*HW+hw];
        float xc = (rx + (float)gx) * st, yc = (ry + (float)gy) * st;
        float wd = expf(rw) * st, ht = expf(rh) * st;
        bx = make_float4(xc - 0.5f*wd, yc - 0.5f*ht, xc + 0.5f*wd, yc + 0.5f*ht);
        boxes[idx] = bx;

        float cl = cp[b*HW+hw], ob = op[b*HW+hw];
        clsL[idx] = cl; objL[idx] = ob;
        so = (double)softplusf_(ob);     // dense obj-loss term: bce(x,0) = softplus(x)
        float p = sqrtf(sigmoidf_(cl) * sigmoidf_(ob));
        ccPv = -fmaxf(logf(p), -100.f);
        ccNv = -fmaxf(logf(1.f - p), -100.f);
        ccP[idx] = ccPv; ccN[idx] = ccNv;

        #pragma unroll
        for (int k = 0; k < 5; k++){
            lmkD[idx*10 + 2*k]     = (lp[(b*10 + 2*k)*HW + hw]     + (float)gx) * st;
            lmkD[idx*10 + 2*k + 1] = (lp[(b*10 + 2*k + 1)*HW + hw] + (float)gy) * st;
        }

        mcnt[idx] = 0; mfirst[idx] = 0x7fffffff; mpiou[idx] = 0.f;

        ax = ((float)gx + 0.5f) * st; ay = ((float)gy + 0.5f) * st;
        r = 2.5f * st;
        for (int g = 0; g < NG; g++){
            if (!sval[g]) continue;
            float4 gv = sgb[g];
            bool inb = fminf(fminf(ax-gv.x, gv.z-ax), fminf(ay-gv.y, gv.w-ay)) > 0.f;
            float cx = (gv.x+gv.z)*0.5f, cy = (gv.y+gv.w)*0.5f;
            bool inc = fminf(fminf(ax-(cx-r), (cx+r)-ax), fminf(ay-(cy-r), (cy+r)-ay)) > 0.f;
            f = f || inb || inc;
        }
    }

    // wave-ballot ordered append; write compacted AoS alongside
    unsigned long long m = __ballot(f);
    int lane = tid & 63;
    if (m){
        int ld = __ffsll(m) - 1;
        int base = 0;
        if (lane == ld) base = atomicAdd(&nFg[b], __popcll(m));
        base = __shfl(base, ld);
        if (f){
            int pos = base + __popcll(m & ((1ull << lane) - 1ull));
            fgList[b*NA + pos] = a;
            boxC[b*NA + pos] = bx;
            metaC[b*NA + pos] = make_float4(ax, ay, r, ccPv);
            ccNC[b*NA + pos] = ccNv;
        }
    }

    // block reduction of dense obj loss (no extra global loads)
    sred[tid] = so;
    for (int off = 128; off >= 1; off >>= 1){
        __syncthreads();
        if (tid < off) sred[tid] += sred[tid+off];
    }
    if (tid == 0) pObj[b*NCHUNK + blockIdx.x] = sred[0];
}

// ---------------- Kernel 2: per-(b,g) dyn_k top-k over compacted fg AoS; scatter matches --------
__global__ void __launch_bounds__(SELT) k_select(
    const float4* __restrict__ boxes,
    const int* __restrict__ fgList, const int* __restrict__ nFg,
    const float4* __restrict__ boxC, const float4* __restrict__ metaC, const float* __restrict__ ccNC,
    const float* __restrict__ gtb, const int* __restrict__ gtl, const unsigned char* __restrict__ gtv,
    int* __restrict__ mcnt, int* __restrict__ mfirst, float* __restrict__ mpiou,
    int* __restrict__ mList, int* __restrict__ nM)
{
    int bg = blockIdx.x;
    int b = bg / NG, g = bg - b*NG;
    if (!gtv[b*NG+g]) return;      // uniform for the block; invalid GT matches nothing
    int tid = threadIdx.x;

    __shared__ float sIou[SELT*TK];
    __shared__ float sC[SELT*TK];
    __shared__ int   sI[SELT*TK];
    __shared__ int   sDk;

    const float* gp = &gtb[(size_t)(b*NG+g)*4];
    float4 gb = make_float4(gp[0], gp[1], gp[2], gp[3]);
    bool lab0 = (gtl[b*NG+g] == 0);
    int nf = nFg[b];

    // hoisted GT-derived terms
    float ag = (gb.z - gb.x) * (gb.w - gb.y);
    float cx = (gb.x + gb.z) * 0.5f, cy = (gb.y + gb.w) * 0.5f;

    const float4* bC = boxC  + (size_t)b*NA;
    const float4* mC = metaC + (size_t)b*NA;
    const float*  nC = ccNC  + (size_t)b*NA;
    const int*    fL = fgList + (size_t)b*NA;

    // iou sentinel 0.f == reference's zero rows (sum-safe when nf < TK)
    float mi[TK], mc[TK]; int mx[TK];
    #pragma unroll
    for (int k = 0; k < TK; k++){ mi[k] = 0.f; mc[k] = INFINITY; mx[k] = 0x7fffffff; }

    for (int i = tid; i < nf; i += SELT){
        float4 bxv = bC[i];
        float4 mt  = mC[i];
        int ia = fL[i];
        // iou
        float tlx = fmaxf(gb.x, bxv.x), tly = fmaxf(gb.y, bxv.y);
        float brx = fminf(gb.z, bxv.z), bry = fminf(gb.w, bxv.w);
        float iw = fmaxf(brx - tlx, 0.f), ih = fmaxf(bry - tly, 0.f);
        float inter = iw * ih;
        float ab = (bxv.z - bxv.x) * (bxv.w - bxv.y);
        float im = inter / (ag + ab - inter + 1e-8f);
        // center tests (anchor geometry precomputed)
        float ax = mt.x, ay = mt.y, r = mt.z;
        bool inb = fminf(fminf(ax-gb.x, gb.z-ax), fminf(ay-gb.y, gb.w-ay)) > 0.f;
        bool inc = fminf(fminf(ax-(cx-r), (cx+r)-ax), fminf(ay-(cy-r), (cy+r)-ay)) > 0.f;
        float cc = mt.w;
        if (!lab0) cc = nC[i];
        float c = cc - 3.f * logf(im + 1e-8f);
        if (!(inb && inc)) c += 1e5f;
        // insert iou (descending) — skip when it can't enter
        if (im > mi[TK-1]){
            float v = im;
            #pragma unroll
            for (int k = 0; k < TK; k++){
                if (v > mi[k]){ float t = mi[k]; mi[k] = v; v = t; }
            }
        }
        // insert (cost, idx) lex ascending — skip when it can't enter
        if ((c < mc[TK-1]) || (c == mc[TK-1] && ia < mx[TK-1])){
            float cv = c; int iv = ia;
            #pragma unroll
            for (int k = 0; k < TK; k++){
                bool lt = (cv < mc[k]) || (cv == mc[k] && iv < mx[k]);
                if (lt){
                    float t = mc[k]; mc[k] = cv; cv = t;
                    int ti = mx[k]; mx[k] = iv; iv = ti;
                }
            }
        }
    }

    #pragma unroll
    for (int k = 0; k < TK; k++){
        sIou[tid*TK+k] = mi[k];
        sC[tid*TK+k] = mc[k];
        sI[tid*TK+k] = mx[k];
    }

    for (int off = SELT/2; off >= 1; off >>= 1){
        __syncthreads();
        if (tid < off){
            { // merge descending iou lists
                float* Al = &sIou[tid*TK]; float* Bl = &sIou[(tid+off)*TK];
                float r2[TK]; int i = 0, j = 0;
                for (int k = 0; k < TK; k++){
                    bool ta = (j >= TK) || (i < TK && Al[i] >= Bl[j]);
                    r2[k] = ta ? Al[i++] : Bl[j++];
                }
                for (int k = 0; k < TK; k++) Al[k] = r2[k];
            }
            { // merge ascending lex (cost, idx) lists
                float* Ac = &sC[tid*TK]; int* Ai = &sI[tid*TK];
                float* Bc = &sC[(tid+off)*TK]; int* Bi = &sI[(tid+off)*TK];
                float rc[TK]; int ri[TK]; int i = 0, j = 0;
                for (int k = 0; k < TK; k++){
                    bool ta = (j >= TK) || (i < TK &&
                        (Ac[i] < Bc[j] || (Ac[i] == Bc[j] && Ai[i] <= Bi[j])));
                    if (ta){ rc[k] = Ac[i]; ri[k] = Ai[i]; i++; }
                    else   { rc[k] = Bc[j]; ri[k] = Bi[j]; j++; }
                }
                for (int k = 0; k < TK; k++){ Ac[k] = rc[k]; Ai[k] = ri[k]; }
            }
        }
    }
    __syncthreads();
    if (tid == 0){
        float s = 0.f;
        for (int k = 0; k < TK; k++) s += sIou[k];
        int dk = (int)s;
        if (dk < 1) dk = 1;
        if (dk > TK) dk = TK;
        sDk = dk;
    }
    __syncthreads();
    int dk = sDk;
    // matched set = first dk entries of the lex-sorted (cost, idx) list
    if (tid < dk){
        int a = sI[tid];
        if (a != 0x7fffffff){       // skip sentinels when nf < dk
            int idx = b*NA + a;
            int old = atomicAdd(&mcnt[idx], 1);
            if (old == 0){          // first match appends anchor to compact matched list
                int p = atomicAdd(&nM[b], 1);
                mList[b*MCAP + p] = a;
            }
            atomicMin(&mfirst[idx], g);
            float4 bxv = boxes[idx];
            float tlx = fmaxf(gb.x, bxv.x), tly = fmaxf(gb.y, bxv.y);
            float brx = fminf(gb.z, bxv.z), bry = fminf(gb.w, bxv.w);
            float iw = fmaxf(brx - tlx, 0.f), ih = fmaxf(bry - tly, 0.f);
            float inter = iw * ih;
            float ab = (bxv.z - bxv.x) * (bxv.w - bxv.y);
            float im = inter / (ag + ab - inter + 1e-8f);
            atomicAdd(&mpiou[idx], im);   // single contributor when cnt==1 (only case it's read)
        }
    }
}

// ---------------- Kernel 3: fg-only losses + fused final combine -------------------------------
__global__ void __launch_bounds__(256) k_fg_loss(
    const float4* __restrict__ boxes, const float* __restrict__ objL, const float* __restrict__ clsL,
    const float* __restrict__ lmkD, const float* __restrict__ ccP, const float* __restrict__ ccN,
    const int* __restrict__ mcnt, const int* __restrict__ mfirst, const float* __restrict__ mpiou,
    const int* __restrict__ mList, const int* __restrict__ nM,
    const float* __restrict__ gtb, const float* __restrict__ gtlm, const int* __restrict__ gtl,
    const unsigned char* __restrict__ gtv, double* __restrict__ partials,
    const double* __restrict__ pObj, int* __restrict__ done, float* __restrict__ out)
{
    __shared__ float4 sgb[NG];
    __shared__ int slab[NG];
    __shared__ unsigned char sval[NG];
    __shared__ float slmk[NG*10];
    int b = blockIdx.y;
    int tid = threadIdx.x;
    if (tid < NG){
        const float* gp = &gtb[(size_t)(b*NG+tid)*4];
        sgb[tid] = make_float4(gp[0], gp[1], gp[2], gp[3]);
        slab[tid] = gtl[b*NG+tid];
        sval[tid] = gtv[b*NG+tid];
    }
    for (int i = tid; i < NG*10; i += 256) slmk[i] = gtlm[(size_t)b*NG*10 + i];
    __syncthreads();

    int n = nM[b];
    double lo = 0, lc = 0, li = 0, lnum = 0, lden = 0, nfg = 0;

    for (int i = blockIdx.x*256 + tid; i < n; i += FGB*256){
        int a = mList[b*MCAP + i];
        int idx = b*NA + a;
        int cnt = mcnt[idx];
        float4 bx = boxes[idx];
        float pious; int m;
        if (cnt == 1){ m = mfirst[idx]; pious = mpiou[idx]; }
        else {
            // conflict: argmin cost over ALL GTs (reference's keep = argmin, first-min on ties)
            int lvl, hw, gx, gy; float st;
            anchor_geom(a, lvl, hw, gx, gy, st);
            float ax = ((float)gx + 0.5f) * st, ay = ((float)gy + 0.5f) * st, r = 2.5f * st;
            float cp = ccP[idx], cn = ccN[idx];
            float ab = (bx.z - bx.x) * (bx.w - bx.y);
            float bestC = INFINITY, bestIou = 0.f; int bestG = 0;
            for (int g = 0; g < NG; g++){
                float4 gbv = sgb[g];
                int valid = sval[g];
                float tlx = fmaxf(gbv.x, bx.x), tly = fmaxf(gbv.y, bx.y);
                float brx = fminf(gbv.z, bx.z), bry = fminf(gbv.w, bx.w);
                float iw = fmaxf(brx - tlx, 0.f), ih = fmaxf(bry - tly, 0.f);
                float inter = iw * ih;
                float agv = (gbv.z - gbv.x) * (gbv.w - gbv.y);
                float im = inter / (agv + ab - inter + 1e-8f);
                bool inb = (fminf(fminf(ax-gbv.x, gbv.z-ax), fminf(ay-gbv.y, gbv.w-ay)) > 0.f) && valid;
                float cxg = (gbv.x + gbv.z) * 0.5f, cyg = (gbv.y + gbv.w) * 0.5f;
                bool inc = (fminf(fminf(ax-(cxg-r), (cxg+r)-ax), fminf(ay-(cyg-r), (cyg+r)-ay)) > 0.f) && valid;
                float cc = (slab[g] == 0) ? cp : cn;
                float c = cc - 3.f * logf(im + 1e-8f);
                if (!(inb && inc)) c += 1e5f;
                if (!valid) c += 1e9f;
                if (c < bestC){ bestC = c; bestG = g; bestIou = im; }
            }
            m = bestG; pious = bestIou;
        }
        lo += (double)(-objL[idx]);              // bce(x,1) - bce(x,0) = -x  (fg correction)
        float tgt = (slab[m] == 0) ? pious : 0.f;
        lc += (double)bce_(clsL[idx], tgt);
        li += (double)(1.f - giou_(bx, sgb[m]));
        #pragma unroll
        for (int k = 0; k < 5; k++){
            float tx = slmk[m*10 + 2*k];
            float ty = slmk[m*10 + 2*k + 1];
            if (tx >= 0.f && ty >= 0.f){
                lnum += (double)(sl1_(lmkD[idx*10 + 2*k] - tx) + sl1_(lmkD[idx*10 + 2*k + 1] - ty));
                lden += 1.0;
            }
        }
        nfg += 1.0;
    }

    __shared__ double s[6*256];
    s[0*256+tid] = lo; s[1*256+tid] = lc; s[2*256+tid] = li;
    s[3*256+tid] = lnum; s[4*256+tid] = lden; s[5*256+tid] = nfg;
    for (int off = 128; off >= 1; off >>= 1){
        __syncthreads();
        if (tid < off){
            #pragma unroll
            for (int q = 0; q < 6; q++) s[q*256+tid] += s[q*256+tid+off];
        }
    }
    if (tid == 0){
        #pragma unroll
        for (int q = 0; q < 6; q++) partials[(b*FGB + blockIdx.x)*6 + q] = s[q*256];
    }

    // ---- fused final combine: last block to finish does the reduction ----
    __threadfence();
    __shared__ int sLast;
    if (tid == 0) sLast = (atomicAdd(done, 1) == NB*FGB - 1);
    __syncthreads();
    if (!sLast) return;

    __shared__ double sf[NB][5];   // lo, lc, li, ll, nfg per image
    if (tid < NB){
        double flo = 0, flc = 0, fli = 0, fln = 0, fld = 0, fnf = 0;
        for (int ch = 0; ch < NCHUNK; ch++) flo += pObj[tid*NCHUNK + ch];
        for (int blk = 0; blk < FGB; blk++){
            const double* p = &partials[(tid*FGB + blk)*6];
            flo += p[0]; flc += p[1]; fli += p[2];
            fln += p[3]; fld += p[4]; fnf += p[5];
        }
        sf[tid][0] = flo; sf[tid][1] = flc; sf[tid][2] = fli;
        sf[tid][3] = fln / fmax(fld, 1.0); sf[tid][4] = fnf;
    }
    __syncthreads();
    if (tid == 0){
        double flo = 0, flc = 0, fli = 0, fll = 0, fnfg = 0;
        for (int bb = 0; bb < NB; bb++){
            flo += sf[bb][0]; flc += sf[bb][1]; fli += sf[bb][2]; fll += sf[bb][3]; fnfg += sf[bb][4];
        }
        double nf2 = fmax(fnfg, 1.0);
        double liou = 5.0 * fli / nf2;
        double lobj = 1.0 * flo / nf2;
        double lcls = 1.0 * flc / nf2;
        double llmk = 5.0 * fll / nf2;
        out[0] = (float)(liou + lobj + lcls + llmk);
        out[1] = (float)liou;
        out[2] = (float)lobj;
        out[3] = (float)lcls;
        out[4] = (float)llmk;
    }
}

extern "C" void kernel_launch(void* const* d_in, const int* in_sizes, int n_in,
                              void* d_out, int out_size, void* d_ws, size_t ws_size,
                              hipStream_t stream) {
    const float* cls0 = (const float*)d_in[0];
    const float* reg0 = (const float*)d_in[1];
    const float* obj0 = (const float*)d_in[2];
    const float* lmk0 = (const float*)d_in[3];
    const float* cls1 = (const float*)d_in[4];
    const float* reg1 = (const float*)d_in[5];
    const float* obj1 = (const float*)d_in[6];
    const float* lmk1 = (const float*)d_in[7];
    const float* cls2 = (const float*)d_in[8];
    const float* reg2 = (const float*)d_in[9];
    const float* obj2 = (const float*)d_in[10];
    const float* lmk2 = (const float*)d_in[11];
    const float* gtb  = (const float*)d_in[12];
    const float* gtlm = (const float*)d_in[13];
    const int*   gtl  = (const int*)d_in[14];
    const unsigned char* gtv_raw = (const unsigned char*)d_in[15];
    float* out = (float*)d_out;

    char* ws = (char*)d_ws;
    size_t off = 0;
    float4* boxes = (float4*)(ws + off); off += (size_t)NB*NA*sizeof(float4);
    float4* boxC  = (float4*)(ws + off); off += (size_t)NB*NA*sizeof(float4);
    float4* metaC = (float4*)(ws + off); off += (size_t)NB*NA*sizeof(float4);
    float* lmkD = (float*)(ws + off); off += (size_t)NB*NA*10*sizeof(float);
    float* objL = (float*)(ws + off); off += (size_t)NB*NA*sizeof(float);
    float* clsL = (float*)(ws + off); off += (size_t)NB*NA*sizeof(float);
    float* ccP  = (float*)(ws + off); off += (size_t)NB*NA*sizeof(float);
    float* ccN  = (float*)(ws + off); off += (size_t)NB*NA*sizeof(float);
    float* ccNC = (float*)(ws + off); off += (size_t)NB*NA*sizeof(float);
    float* mpiou = (float*)(ws + off); off += (size_t)NB*NA*sizeof(float);
    int* mcnt   = (int*)(ws + off);   off += (size_t)NB*NA*sizeof(int);
    int* mfirst = (int*)(ws + off);   off += (size_t)NB*NA*sizeof(int);
    int* fgList = (int*)(ws + off);   off += (size_t)NB*NA*sizeof(int);
    int* mList  = (int*)(ws + off);   off += (size_t)NB*MCAP*sizeof(int);
    int* nFg    = (int*)(ws + off);   off += (size_t)64;
    int* nM     = (int*)(ws + off);   off += (size_t)64;
    int* done   = (int*)(ws + off);   off += (size_t)64;
    double* pObj = (double*)(ws + off); off += (size_t)NB*NCHUNK*sizeof(double);
    double* partials = (double*)(ws + off); off += (size_t)NB*FGB*6*sizeof(double);
    unsigned char* gtv = (unsigned char*)(ws + off); off += (size_t)NB*NG;

    k_init<<<dim3(1), dim3(256), 0, stream>>>(gtv_raw, gtv, nFg, nM, done);

    dim3 grdA(NCHUNK, NB);
    k_decode<<<grdA, dim3(256), 0, stream>>>(cls0, reg0, obj0, lmk0, cls1, reg1, obj1, lmk1,
                                             cls2, reg2, obj2, lmk2, gtb, gtv,
                                             boxes, objL, clsL, lmkD, ccP, ccN,
                                             fgList, nFg, boxC, metaC, ccNC,
                                             mcnt, mfirst, mpiou, pObj);

    k_select<<<dim3(NB*NG), dim3(SELT), 0, stream>>>(boxes, fgList, nFg, boxC, metaC, ccNC,
                                                     gtb, gtl, gtv, mcnt, mfirst, mpiou,
                                                     mList, nM);

    k_fg_loss<<<dim3(FGB, NB), dim3(256), 0, stream>>>(boxes, objL, clsL, lmkD, ccP, ccN,
                                                       mcnt, mfirst, mpiou, mList, nM,
                                                       gtb, gtlm, gtl, gtv, partials,
                                                       pObj, done, out);
}

// Round 4
// 96.883 us; speedup vs baseline: 2.3941x; 1.1533x over previous
//
#include <hip/hip_runtime.h>
#include <math.h>

#define NB 16
#define NA 8400
#define NG 50
#define TK 10
#define SELT 256
#define NCHUNK 33   // ceil(NA/256)
#define FGB 2       // fg-loss blocks per image (2*256 >= TK*NG=500 max matched)
#define MCAP 512    // matched-list capacity per image

__device__ __forceinline__ float sigmoidf_(float x){ return 1.f/(1.f+expf(-x)); }
__device__ __forceinline__ float softplusf_(float x){ return log1pf(expf(-fabsf(x))) + fmaxf(x, 0.f); }
__device__ __forceinline__ float bce_(float x, float t){ return softplusf_(x) - x*t; }
__device__ __forceinline__ float sl1_(float d){
    const float B = 1.f/9.f;
    float a = fabsf(d);
    return a < B ? 0.5f*a*a/B : a - 0.5f*B;
}

__device__ __forceinline__ void anchor_geom(int a, int& lvl, int& hw, int& gx, int& gy, float& st){
    if (a < 6400){ lvl=0; hw=a;      gx=hw%80; gy=hw/80; st=8.f; }
    else if (a < 8000){ lvl=1; hw=a-6400; gx=hw%40; gy=hw/40; st=16.f; }
    else { lvl=2; hw=a-8000; gx=hw%20; gy=hw/20; st=32.f; }
}

__device__ __forceinline__ float giou_(float4 a, float4 b){
    float tlx = fmaxf(a.x,b.x), tly = fmaxf(a.y,b.y);
    float brx = fminf(a.z,b.z), bry = fminf(a.w,b.w);
    float iw = fmaxf(brx-tlx,0.f), ih = fmaxf(bry-tly,0.f);
    float inter = iw*ih;
    float aa = (a.z-a.x)*(a.w-a.y);
    float ab = (b.z-b.x)*(b.w-b.y);
    float uni = aa + ab - inter;
    float iou = inter / (uni + 1e-8f);
    float ctlx = fminf(a.x,b.x), ctly = fminf(a.y,b.y);
    float cbrx = fmaxf(a.z,b.z), cbry = fmaxf(a.w,b.w);
    float cw = fmaxf(cbrx-ctlx,0.f), ch = fmaxf(cbry-ctly,0.f);
    float ca = cw*ch;
    return iou - (ca - uni) / (ca + 1e-8f);
}

// ---------------- Kernel 1: decode + precompute + dense obj-loss + ordered fg compaction --------
// ctr layout: [0..15]=nFg per image, [16..31]=nM per image, [32]=done counter (memset to 0).
// Each block normalizes gt_valid (byte vs int32 bool) locally; blockIdx.x==0 publishes it.
__global__ void __launch_bounds__(256) k_decode(
    const float* __restrict__ cls0, const float* __restrict__ reg0, const float* __restrict__ obj0, const float* __restrict__ lmk0,
    const float* __restrict__ cls1, const float* __restrict__ reg1, const float* __restrict__ obj1, const float* __restrict__ lmk1,
    const float* __restrict__ cls2, const float* __restrict__ reg2, const float* __restrict__ obj2, const float* __restrict__ lmk2,
    const float* __restrict__ gtb, const unsigned char* __restrict__ gtv_raw, unsigned char* __restrict__ gtv,
    float4* __restrict__ boxes, float* __restrict__ objL, float* __restrict__ clsL,
    float* __restrict__ lmkD, float* __restrict__ ccP, float* __restrict__ ccN,
    int* __restrict__ fgList, int* __restrict__ ctr,
    float4* __restrict__ boxC, float4* __restrict__ metaC,
    float* __restrict__ ccPC, float* __restrict__ ccNC,
    int* __restrict__ mcnt, int* __restrict__ mfirst, float* __restrict__ mpiou,
    double* __restrict__ pObj)
{
    __shared__ float4 sgb[NG];
    __shared__ unsigned char sval[NG];
    __shared__ int sIsByte;
    __shared__ double sred[256];
    int b = blockIdx.y;
    int tid = threadIdx.x;

    if (tid == 0) sIsByte = 0;
    if (tid < NG){
        const float* gp = &gtb[(size_t)(b*NG+tid)*4];
        sgb[tid] = make_float4(gp[0], gp[1], gp[2], gp[3]);
    }
    __syncthreads();
    {   // byte-layout iff any non-multiple-of-4 byte of the first NB*NG bytes is nonzero
        int any = 0;
        for (int i = tid; i < NB*NG; i += 256) if ((i & 3) && gtv_raw[i]) any = 1;
        if (any) sIsByte = 1;          // benign race, all write 1
    }
    __syncthreads();
    if (tid < NG){
        unsigned char vv = sIsByte ? (gtv_raw[b*NG+tid] != 0) : (gtv_raw[4*(b*NG+tid)] != 0);
        sval[tid] = vv;
        if (blockIdx.x == 0) gtv[b*NG+tid] = vv;
    }
    __syncthreads();

    int a = blockIdx.x * 256 + tid;
    bool act = (a < NA);
    double so = 0.0;
    bool f = false;
    float4 bx; float ax = 0.f, ay = 0.f, r = 0.f, abv = 0.f, ccPv = 0.f, ccNv = 0.f;
    if (act){
        int idx = b*NA + a;
        int lvl, hw, gx, gy; float st;
        anchor_geom(a, lvl, hw, gx, gy, st);
        const float* cp = lvl==0?cls0:(lvl==1?cls1:cls2);
        const float* rp = lvl==0?reg0:(lvl==1?reg1:reg2);
        const float* op = lvl==0?obj0:(lvl==1?obj1:obj2);
        const float* lp = lvl==0?lmk0:(lvl==1?lmk1:lmk2);
        int HW = lvl==0?6400:(lvl==1?1600:400);

        float rx = rp[(b*4+0)*HW+hw], ry = rp[(b*4+1)*HW+hw];
        float rw = rp[(b*4+2)*HW+hw], rh = rp[(b*4+3)*HW+hw];
        float xc = (rx + (float)gx) * st, yc = (ry + (float)gy) * st;
        float wd = expf(rw) * st, ht = expf(rh) * st;
        bx = make_float4(xc - 0.5f*wd, yc - 0.5f*ht, xc + 0.5f*wd, yc + 0.5f*ht);
        boxes[idx] = bx;
        abv = (bx.z - bx.x) * (bx.w - bx.y);

        float cl = cp[b*HW+hw], ob = op[b*HW+hw];
        clsL[idx] = cl; objL[idx] = ob;
        so = (double)softplusf_(ob);     // dense obj-loss term: bce(x,0) = softplus(x)
        float p = sqrtf(sigmoidf_(cl) * sigmoidf_(ob));
        ccPv = -fmaxf(logf(p), -100.f);
        ccNv = -fmaxf(logf(1.f - p), -100.f);
        ccP[idx] = ccPv; ccN[idx] = ccNv;

        #pragma unroll
        for (int k = 0; k < 5; k++){
            lmkD[idx*10 + 2*k]     = (lp[(b*10 + 2*k)*HW + hw]     + (float)gx) * st;
            lmkD[idx*10 + 2*k + 1] = (lp[(b*10 + 2*k + 1)*HW + hw] + (float)gy) * st;
        }

        mcnt[idx] = 0; mfirst[idx] = 0x7fffffff; mpiou[idx] = 0.f;

        ax = ((float)gx + 0.5f) * st; ay = ((float)gy + 0.5f) * st;
        r = 2.5f * st;
        for (int g = 0; g < NG; g++){
            if (!sval[g]) continue;
            float4 gv = sgb[g];
            bool inb = fminf(fminf(ax-gv.x, gv.z-ax), fminf(ay-gv.y, gv.w-ay)) > 0.f;
            float cx = (gv.x+gv.z)*0.5f, cy = (gv.y+gv.w)*0.5f;
            bool inc = fminf(fminf(ax-(cx-r), (cx+r)-ax), fminf(ay-(cy-r), (cy+r)-ay)) > 0.f;
            f = f || inb || inc;
        }
    }

    // wave-ballot ordered append; write compacted AoS alongside
    unsigned long long m = __ballot(f);
    int lane = tid & 63;
    if (m){
        int ld = __ffsll(m) - 1;
        int base = 0;
        if (lane == ld) base = atomicAdd(&ctr[b], __popcll(m));
        base = __shfl(base, ld);
        if (f){
            int pos = base + __popcll(m & ((1ull << lane) - 1ull));
            fgList[b*NA + pos] = a;
            boxC[b*NA + pos] = bx;
            metaC[b*NA + pos] = make_float4(ax, ay, r, abv);
            ccPC[b*NA + pos] = ccPv;
            ccNC[b*NA + pos] = ccNv;
        }
    }

    // block reduction of dense obj loss (no extra global loads)
    sred[tid] = so;
    for (int off = 128; off >= 1; off >>= 1){
        __syncthreads();
        if (tid < off) sred[tid] += sred[tid+off];
    }
    if (tid == 0) pObj[b*NCHUNK + blockIdx.x] = sred[0];
}

// ---------------- Kernel 2: per-(b,g) dyn_k top-k over compacted fg AoS; scatter matches --------
// (cost, idx) kept as one sortable u64: monotone-float-key(cost)<<32 | idx — u64 '<' == lex order.
__global__ void __launch_bounds__(SELT) k_select(
    const float4* __restrict__ boxes,
    const int* __restrict__ fgList, const int* __restrict__ ctr,
    const float4* __restrict__ boxC, const float4* __restrict__ metaC,
    const float* __restrict__ ccPC, const float* __restrict__ ccNC,
    const float* __restrict__ gtb, const int* __restrict__ gtl, const unsigned char* __restrict__ gtv,
    int* __restrict__ mcnt, int* __restrict__ mfirst, float* __restrict__ mpiou,
    int* __restrict__ mList)
{
    int bg = blockIdx.x;
    int b = bg / NG, g = bg - b*NG;
    if (!gtv[b*NG+g]) return;      // uniform for the block; invalid GT matches nothing
    int tid = threadIdx.x;

    __shared__ float sIou[SELT*TK];
    __shared__ unsigned long long sK[SELT*TK];
    __shared__ int sDk;

    const float* gp = &gtb[(size_t)(b*NG+g)*4];
    float4 gb = make_float4(gp[0], gp[1], gp[2], gp[3]);
    bool lab0 = (gtl[b*NG+g] == 0);
    int nf = ctr[b];

    // hoisted GT-derived terms
    float ag = (gb.z - gb.x) * (gb.w - gb.y);
    float cx = (gb.x + gb.z) * 0.5f, cy = (gb.y + gb.w) * 0.5f;

    const float4* bC = boxC  + (size_t)b*NA;
    const float4* mC = metaC + (size_t)b*NA;
    const float*  cS = (lab0 ? ccPC : ccNC) + (size_t)b*NA;
    const int*    fL = fgList + (size_t)b*NA;

    // iou sentinel 0.f == reference's zero rows; key sentinel = all-ones (> any real key)
    float mi[TK]; unsigned long long mk[TK];
    #pragma unroll
    for (int k = 0; k < TK; k++){ mi[k] = 0.f; mk[k] = 0xFFFFFFFFFFFFFFFFull; }

    // manually software-pipelined scan: issue iteration i+1's loads before processing i
    int i = tid;
    float4 bxv, mt; float ccv; unsigned int ia;
    if (i < nf){ bxv = bC[i]; mt = mC[i]; ccv = cS[i]; ia = (unsigned int)fL[i]; }
    while (i < nf){
        int i2 = i + SELT;
        float4 bxv2, mt2; float ccv2; unsigned int ia2;
        if (i2 < nf){ bxv2 = bC[i2]; mt2 = mC[i2]; ccv2 = cS[i2]; ia2 = (unsigned int)fL[i2]; }
        // iou
        float tlx = fmaxf(gb.x, bxv.x), tly = fmaxf(gb.y, bxv.y);
        float brx = fminf(gb.z, bxv.z), bry = fminf(gb.w, bxv.w);
        float iw = fmaxf(brx - tlx, 0.f), ih = fmaxf(bry - tly, 0.f);
        float inter = iw * ih;
        float im = inter / (ag + mt.w - inter + 1e-8f);
        // center tests (anchor geometry precomputed)
        float ax = mt.x, ay = mt.y, r = mt.z;
        bool inb = fminf(fminf(ax-gb.x, gb.z-ax), fminf(ay-gb.y, gb.w-ay)) > 0.f;
        bool inc = fminf(fminf(ax-(cx-r), (cx+r)-ax), fminf(ay-(cy-r), (cy+r)-ay)) > 0.f;
        float c = ccv - 3.f * logf(im + 1e-8f);
        if (!(inb && inc)) c += 1e5f;
        // insert iou (descending)
        if (im > mi[TK-1]){
            float v = im;
            #pragma unroll
            for (int k = 0; k < TK; k++){
                if (v > mi[k]){ float t = mi[k]; mi[k] = v; v = t; }
            }
        }
        // insert packed (cost, idx) ascending
        unsigned int fb = __float_as_uint(c);
        unsigned int ck = fb ^ ((unsigned int)((int)fb >> 31) | 0x80000000u);
        unsigned long long key = ((unsigned long long)ck << 32) | ia;
        if (key < mk[TK-1]){
            unsigned long long kv = key;
            #pragma unroll
            for (int k = 0; k < TK; k++){
                if (kv < mk[k]){ unsigned long long t = mk[k]; mk[k] = kv; kv = t; }
            }
        }
        i = i2; bxv = bxv2; mt = mt2; ccv = ccv2; ia = ia2;
    }

    #pragma unroll
    for (int k = 0; k < TK; k++){
        sIou[tid*TK+k] = mi[k];
        sK[tid*TK+k] = mk[k];
    }

    for (int off = SELT/2; off >= 1; off >>= 1){
        __syncthreads();
        if (tid < off){
            { // merge descending iou lists
                float* Al = &sIou[tid*TK]; float* Bl = &sIou[(tid+off)*TK];
                float r2[TK]; int ii = 0, jj = 0;
                for (int k = 0; k < TK; k++){
                    bool ta = (jj >= TK) || (ii < TK && Al[ii] >= Bl[jj]);
                    r2[k] = ta ? Al[ii++] : Bl[jj++];
                }
                for (int k = 0; k < TK; k++) Al[k] = r2[k];
            }
            { // merge ascending u64 key lists
                unsigned long long* Ak = &sK[tid*TK]; unsigned long long* Bk = &sK[(tid+off)*TK];
                unsigned long long rk[TK]; int ii = 0, jj = 0;
                for (int k = 0; k < TK; k++){
                    bool ta = (jj >= TK) || (ii < TK && Ak[ii] <= Bk[jj]);
                    rk[k] = ta ? Ak[ii++] : Bk[jj++];
                }
                for (int k = 0; k < TK; k++) Ak[k] = rk[k];
            }
        }
    }
    __syncthreads();
    if (tid == 0){
        float s = 0.f;
        for (int k = 0; k < TK; k++) s += sIou[k];
        int dk = (int)s;
        if (dk < 1) dk = 1;
        if (dk > TK) dk = TK;
        sDk = dk;
    }
    __syncthreads();
    int dk = sDk;
    // matched set = first dk entries of the sorted key list
    if (tid < dk){
        unsigned long long kk = sK[tid];
        unsigned int a = (unsigned int)(kk & 0xFFFFFFFFull);
        if (a < (unsigned int)NA){      // skip sentinels when nf < dk
            int idx = b*NA + (int)a;
            int old = atomicAdd(&mcnt[idx], 1);
            if (old == 0){              // first match appends anchor to compact matched list
                int p = atomicAdd((int*)&ctr[16 + b], 1);
                mList[b*MCAP + p] = (int)a;
            }
            atomicMin(&mfirst[idx], g);
            float4 bxv = boxes[idx];
            float tlx = fmaxf(gb.x, bxv.x), tly = fmaxf(gb.y, bxv.y);
            float brx = fminf(gb.z, bxv.z), bry = fminf(gb.w, bxv.w);
            float iw = fmaxf(brx - tlx, 0.f), ih = fmaxf(bry - tly, 0.f);
            float inter = iw * ih;
            float ab = (bxv.z - bxv.x) * (bxv.w - bxv.y);
            float im = inter / (ag + ab - inter + 1e-8f);
            atomicAdd(&mpiou[idx], im);   // single contributor when cnt==1 (only case it's read)
        }
    }
}

// ---------------- Kernel 3: fg-only losses + fused final combine -------------------------------
__global__ void __launch_bounds__(256) k_fg_loss(
    const float4* __restrict__ boxes, const float* __restrict__ objL, const float* __restrict__ clsL,
    const float* __restrict__ lmkD, const float* __restrict__ ccP, const float* __restrict__ ccN,
    const int* __restrict__ mcnt, const int* __restrict__ mfirst, const float* __restrict__ mpiou,
    const int* __restrict__ mList, int* __restrict__ ctr,
    const float* __restrict__ gtb, const float* __restrict__ gtlm, const int* __restrict__ gtl,
    const unsigned char* __restrict__ gtv, double* __restrict__ partials,
    const double* __restrict__ pObj, float* __restrict__ out)
{
    __shared__ float4 sgb[NG];
    __shared__ int slab[NG];
    __shared__ unsigned char sval[NG];
    __shared__ float slmk[NG*10];
    int b = blockIdx.y;
    int tid = threadIdx.x;
    if (tid < NG){
        const float* gp = &gtb[(size_t)(b*NG+tid)*4];
        sgb[tid] = make_float4(gp[0], gp[1], gp[2], gp[3]);
        slab[tid] = gtl[b*NG+tid];
        sval[tid] = gtv[b*NG+tid];
    }
    for (int i = tid; i < NG*10; i += 256) slmk[i] = gtlm[(size_t)b*NG*10 + i];
    __syncthreads();

    int n = ctr[16 + b];
    double lo = 0, lc = 0, li = 0, lnum = 0, lden = 0, nfg = 0;

    for (int i = blockIdx.x*256 + tid; i < n; i += FGB*256){
        int a = mList[b*MCAP + i];
        int idx = b*NA + a;
        int cnt = mcnt[idx];
        float4 bx = boxes[idx];
        float pious; int m;
        if (cnt == 1){ m = mfirst[idx]; pious = mpiou[idx]; }
        else {
            // conflict: argmin cost over ALL GTs (reference's keep = argmin, first-min on ties)
            int lvl, hw, gx, gy; float st;
            anchor_geom(a, lvl, hw, gx, gy, st);
            float ax = ((float)gx + 0.5f) * st, ay = ((float)gy + 0.5f) * st, r = 2.5f * st;
            float cp = ccP[idx], cn = ccN[idx];
            float ab = (bx.z - bx.x) * (bx.w - bx.y);
            float bestC = INFINITY, bestIou = 0.f; int bestG = 0;
            for (int g = 0; g < NG; g++){
                float4 gbv = sgb[g];
                int valid = sval[g];
                float tlx = fmaxf(gbv.x, bx.x), tly = fmaxf(gbv.y, bx.y);
                float brx = fminf(gbv.z, bx.z), bry = fminf(gbv.w, bx.w);
                float iw = fmaxf(brx - tlx, 0.f), ih = fmaxf(bry - tly, 0.f);
                float inter = iw * ih;
                float agv = (gbv.z - gbv.x) * (gbv.w - gbv.y);
                float im = inter / (agv + ab - inter + 1e-8f);
                bool inb = (fminf(fminf(ax-gbv.x, gbv.z-ax), fminf(ay-gbv.y, gbv.w-ay)) > 0.f) && valid;
                float cxg = (gbv.x + gbv.z) * 0.5f, cyg = (gbv.y + gbv.w) * 0.5f;
                bool inc = (fminf(fminf(ax-(cxg-r), (cxg+r)-ax), fminf(ay-(cyg-r), (cyg+r)-ay)) > 0.f) && valid;
                float cc = (slab[g] == 0) ? cp : cn;
                float c = cc - 3.f * logf(im + 1e-8f);
                if (!(inb && inc)) c += 1e5f;
                if (!valid) c += 1e9f;
                if (c < bestC){ bestC = c; bestG = g; bestIou = im; }
            }
            m = bestG; pious = bestIou;
        }
        lo += (double)(-objL[idx]);              // bce(x,1) - bce(x,0) = -x  (fg correction)
        float tgt = (slab[m] == 0) ? pious : 0.f;
        lc += (double)bce_(clsL[idx], tgt);
        li += (double)(1.f - giou_(bx, sgb[m]));
        #pragma unroll
        for (int k = 0; k < 5; k++){
            float tx = slmk[m*10 + 2*k];
            float ty = slmk[m*10 + 2*k + 1];
            if (tx >= 0.f && ty >= 0.f){
                lnum += (double)(sl1_(lmkD[idx*10 + 2*k] - tx) + sl1_(lmkD[idx*10 + 2*k + 1] - ty));
                lden += 1.0;
            }
        }
        nfg += 1.0;
    }

    __shared__ double s[6*256];
    s[0*256+tid] = lo; s[1*256+tid] = lc; s[2*256+tid] = li;
    s[3*256+tid] = lnum; s[4*256+tid] = lden; s[5*256+tid] = nfg;
    for (int off = 128; off >= 1; off >>= 1){
        __syncthreads();
        if (tid < off){
            #pragma unroll
            for (int q = 0; q < 6; q++) s[q*256+tid] += s[q*256+tid+off];
        }
    }
    if (tid == 0){
        #pragma unroll
        for (int q = 0; q < 6; q++) partials[(b*FGB + blockIdx.x)*6 + q] = s[q*256];
    }

    // ---- fused final combine: last block to finish does the reduction ----
    __threadfence();
    __shared__ int sLast;
    if (tid == 0) sLast = (atomicAdd(&ctr[32], 1) == NB*FGB - 1);
    __syncthreads();
    if (!sLast) return;

    __shared__ double sf[NB][5];   // lo, lc, li, ll, nfg per image
    if (tid < NB){
        double flo = 0, flc = 0, fli = 0, fln = 0, fld = 0, fnf = 0;
        for (int ch = 0; ch < NCHUNK; ch++) flo += pObj[tid*NCHUNK + ch];
        for (int blk = 0; blk < FGB; blk++){
            const double* p = &partials[(tid*FGB + blk)*6];
            flo += p[0]; flc += p[1]; fli += p[2];
            fln += p[3]; fld += p[4]; fnf += p[5];
        }
        sf[tid][0] = flo; sf[tid][1] = flc; sf[tid][2] = fli;
        sf[tid][3] = fln / fmax(fld, 1.0); sf[tid][4] = fnf;
    }
    __syncthreads();
    if (tid == 0){
        double flo = 0, flc = 0, fli = 0, fll = 0, fnfg = 0;
        for (int bb = 0; bb < NB; bb++){
            flo += sf[bb][0]; flc += sf[bb][1]; fli += sf[bb][2]; fll += sf[bb][3]; fnfg += sf[bb][4];
        }
        double nf2 = fmax(fnfg, 1.0);
        double liou = 5.0 * fli / nf2;
        double lobj = 1.0 * flo / nf2;
        double lcls = 1.0 * flc / nf2;
        double llmk = 5.0 * fll / nf2;
        out[0] = (float)(liou + lobj + lcls + llmk);
        out[1] = (float)liou;
        out[2] = (float)lobj;
        out[3] = (float)lcls;
        out[4] = (float)llmk;
    }
}

extern "C" void kernel_launch(void* const* d_in, const int* in_sizes, int n_in,
                              void* d_out, int out_size, void* d_ws, size_t ws_size,
                              hipStream_t stream) {
    const float* cls0 = (const float*)d_in[0];
    const float* reg0 = (const float*)d_in[1];
    const float* obj0 = (const float*)d_in[2];
    const float* lmk0 = (const float*)d_in[3];
    const float* cls1 = (const float*)d_in[4];
    const float* reg1 = (const float*)d_in[5];
    const float* obj1 = (const float*)d_in[6];
    const float* lmk1 = (const float*)d_in[7];
    const float* cls2 = (const float*)d_in[8];
    const float* reg2 = (const float*)d_in[9];
    const float* obj2 = (const float*)d_in[10];
    const float* lmk2 = (const float*)d_in[11];
    const float* gtb  = (const float*)d_in[12];
    const float* gtlm = (const float*)d_in[13];
    const int*   gtl  = (const int*)d_in[14];
    const unsigned char* gtv_raw = (const unsigned char*)d_in[15];
    float* out = (float*)d_out;

    char* ws = (char*)d_ws;
    size_t off = 0;
    float4* boxes = (float4*)(ws + off); off += (size_t)NB*NA*sizeof(float4);
    float4* boxC  = (float4*)(ws + off); off += (size_t)NB*NA*sizeof(float4);
    float4* metaC = (float4*)(ws + off); off += (size_t)NB*NA*sizeof(float4);
    float* lmkD = (float*)(ws + off); off += (size_t)NB*NA*10*sizeof(float);
    float* objL = (float*)(ws + off); off += (size_t)NB*NA*sizeof(float);
    float* clsL = (float*)(ws + off); off += (size_t)NB*NA*sizeof(float);
    float* ccP  = (float*)(ws + off); off += (size_t)NB*NA*sizeof(float);
    float* ccN  = (float*)(ws + off); off += (size_t)NB*NA*sizeof(float);
    float* ccPC = (float*)(ws + off); off += (size_t)NB*NA*sizeof(float);
    float* ccNC = (float*)(ws + off); off += (size_t)NB*NA*sizeof(float);
    float* mpiou = (float*)(ws + off); off += (size_t)NB*NA*sizeof(float);
    int* mcnt   = (int*)(ws + off);   off += (size_t)NB*NA*sizeof(int);
    int* mfirst = (int*)(ws + off);   off += (size_t)NB*NA*sizeof(int);
    int* fgList = (int*)(ws + off);   off += (size_t)NB*NA*sizeof(int);
    int* mList  = (int*)(ws + off);   off += (size_t)NB*MCAP*sizeof(int);
    int* ctr    = (int*)(ws + off);   off += (size_t)256;   // nFg[16] | nM[16] | done | pad
    double* pObj = (double*)(ws + off); off += (size_t)NB*NCHUNK*sizeof(double);
    double* partials = (double*)(ws + off); off += (size_t)NB*FGB*6*sizeof(double);
    unsigned char* gtv = (unsigned char*)(ws + off); off += (size_t)NB*NG;

    hipMemsetAsync(ctr, 0, 256, stream);

    dim3 grdA(NCHUNK, NB);
    k_decode<<<grdA, dim3(256), 0, stream>>>(cls0, reg0, obj0, lmk0, cls1, reg1, obj1, lmk1,
                                             cls2, reg2, obj2, lmk2, gtb, gtv_raw, gtv,
                                             boxes, objL, clsL, lmkD, ccP, ccN,
                                             fgList, ctr, boxC, metaC, ccPC, ccNC,
                                             mcnt, mfirst, mpiou, pObj);

    k_select<<<dim3(NB*NG), dim3(SELT), 0, stream>>>(boxes, fgList, ctr, boxC, metaC, ccPC, ccNC,
                                                     gtb, gtl, gtv, mcnt, mfirst, mpiou, mList);

    k_fg_loss<<<dim3(FGB, NB), dim3(256), 0, stream>>>(boxes, objL, clsL, lmkD, ccP, ccN,
                                                       mcnt, mfirst, mpiou, mList, ctr,
                                                       gtb, gtlm, gtl, gtv, partials,
                                                       pObj, out);
}

// Round 5
// 77.616 us; speedup vs baseline: 2.9884x; 1.2482x over previous
//
#include <hip/hip_runtime.h>
#include <math.h>

#define NB 16
#define NA 8400
#define NG 50
#define TK 10
#define SELT 256
#define LP 11       // padded per-thread list stride in LDS (bank-conflict mitigation)
#define NCHUNK 33   // ceil(NA/256)
#define FGB 2       // fg-loss blocks per image (2*256 >= TK*NG=500 max matched)
#define MCAP 512    // matched-list capacity per image

// padded counter layout: one 128-B line per counter
#define CTR_FG(b)  ((b)*64)        // nFg per image
#define CTR_M(b)   ((b)*64 + 32)   // nM per image
#define CTR_DONE   (16*64)         // done counter

__device__ __forceinline__ float sigmoidf_(float x){ return 1.f/(1.f+expf(-x)); }
__device__ __forceinline__ float softplusf_(float x){ return log1pf(expf(-fabsf(x))) + fmaxf(x, 0.f); }
__device__ __forceinline__ float bce_(float x, float t){ return softplusf_(x) - x*t; }
__device__ __forceinline__ float sl1_(float d){
    const float B = 1.f/9.f;
    float a = fabsf(d);
    return a < B ? 0.5f*a*a/B : a - 0.5f*B;
}

__device__ __forceinline__ void anchor_geom(int a, int& lvl, int& hw, int& gx, int& gy, float& st){
    if (a < 6400){ lvl=0; hw=a;      gx=hw%80; gy=hw/80; st=8.f; }
    else if (a < 8000){ lvl=1; hw=a-6400; gx=hw%40; gy=hw/40; st=16.f; }
    else { lvl=2; hw=a-8000; gx=hw%20; gy=hw/20; st=32.f; }
}

__device__ __forceinline__ float giou_(float4 a, float4 b){
    float tlx = fmaxf(a.x,b.x), tly = fmaxf(a.y,b.y);
    float brx = fminf(a.z,b.z), bry = fminf(a.w,b.w);
    float iw = fmaxf(brx-tlx,0.f), ih = fmaxf(bry-tly,0.f);
    float inter = iw*ih;
    float aa = (a.z-a.x)*(a.w-a.y);
    float ab = (b.z-b.x)*(b.w-b.y);
    float uni = aa + ab - inter;
    float iou = inter / (uni + 1e-8f);
    float ctlx = fminf(a.x,b.x), ctly = fminf(a.y,b.y);
    float cbrx = fmaxf(a.z,b.z), cbry = fmaxf(a.w,b.w);
    float cw = fmaxf(cbrx-ctlx,0.f), ch = fmaxf(cbry-ctly,0.f);
    float ca = cw*ch;
    return iou - (ca - uni) / (ca + 1e-8f);
}

// ---------------- Kernel 1: decode + precompute + dense obj-loss + ordered fg compaction --------
// One atomic per block (LDS wave-count aggregation); counters padded to own cache lines.
__global__ void __launch_bounds__(256) k_decode(
    const float* __restrict__ cls0, const float* __restrict__ reg0, const float* __restrict__ obj0, const float* __restrict__ lmk0,
    const float* __restrict__ cls1, const float* __restrict__ reg1, const float* __restrict__ obj1, const float* __restrict__ lmk1,
    const float* __restrict__ cls2, const float* __restrict__ reg2, const float* __restrict__ obj2, const float* __restrict__ lmk2,
    const float* __restrict__ gtb, const unsigned char* __restrict__ gtv_raw, unsigned char* __restrict__ gtv,
    float4* __restrict__ boxes, float* __restrict__ objL, float* __restrict__ clsL,
    float* __restrict__ lmkD, float* __restrict__ ccP, float* __restrict__ ccN,
    int* __restrict__ fgList, int* __restrict__ ctr,
    float4* __restrict__ boxC, float4* __restrict__ metaC,
    float* __restrict__ ccPC, float* __restrict__ ccNC,
    int* __restrict__ mcnt, int* __restrict__ mfirst, float* __restrict__ mpiou,
    double* __restrict__ pObj)
{
    __shared__ float4 sgb[NG];
    __shared__ unsigned char sval[NG];
    __shared__ int sIsByte;
    __shared__ int swc[4];
    __shared__ int sbase;
    __shared__ double sred[256];
    int b = blockIdx.y;
    int tid = threadIdx.x;

    if (tid == 0) sIsByte = 0;
    if (tid < NG){
        const float* gp = &gtb[(size_t)(b*NG+tid)*4];
        sgb[tid] = make_float4(gp[0], gp[1], gp[2], gp[3]);
    }
    __syncthreads();
    {   // byte-layout iff any non-multiple-of-4 byte of the first NB*NG bytes is nonzero
        int any = 0;
        for (int i = tid; i < NB*NG; i += 256) if ((i & 3) && gtv_raw[i]) any = 1;
        if (any) sIsByte = 1;          // benign race, all write 1
    }
    __syncthreads();
    if (tid < NG){
        unsigned char vv = sIsByte ? (gtv_raw[b*NG+tid] != 0) : (gtv_raw[4*(b*NG+tid)] != 0);
        sval[tid] = vv;
        if (blockIdx.x == 0) gtv[b*NG+tid] = vv;
    }
    __syncthreads();

    int a = blockIdx.x * 256 + tid;
    bool act = (a < NA);
    double so = 0.0;
    bool f = false;
    float4 bx; float ax = 0.f, ay = 0.f, r = 0.f, abv = 0.f, ccPv = 0.f, ccNv = 0.f;
    if (act){
        int idx = b*NA + a;
        int lvl, hw, gx, gy; float st;
        anchor_geom(a, lvl, hw, gx, gy, st);
        const float* cp = lvl==0?cls0:(lvl==1?cls1:cls2);
        const float* rp = lvl==0?reg0:(lvl==1?reg1:reg2);
        const float* op = lvl==0?obj0:(lvl==1?obj1:obj2);
        const float* lp = lvl==0?lmk0:(lvl==1?lmk1:lmk2);
        int HW = lvl==0?6400:(lvl==1?1600:400);

        float rx = rp[(b*4+0)*HW+hw], ry = rp[(b*4+1)*HW+hw];
        float rw = rp[(b*4+2)*HW+hw], rh = rp[(b*4+3)*HW+hw];
        float xc = (rx + (float)gx) * st, yc = (ry + (float)gy) * st;
        float wd = expf(rw) * st, ht = expf(rh) * st;
        bx = make_float4(xc - 0.5f*wd, yc - 0.5f*ht, xc + 0.5f*wd, yc + 0.5f*ht);
        boxes[idx] = bx;
        abv = (bx.z - bx.x) * (bx.w - bx.y);

        float cl = cp[b*HW+hw], ob = op[b*HW+hw];
        clsL[idx] = cl; objL[idx] = ob;
        so = (double)softplusf_(ob);     // dense obj-loss term: bce(x,0) = softplus(x)
        float p = sqrtf(sigmoidf_(cl) * sigmoidf_(ob));
        ccPv = -fmaxf(logf(p), -100.f);
        ccNv = -fmaxf(logf(1.f - p), -100.f);
        ccP[idx] = ccPv; ccN[idx] = ccNv;

        #pragma unroll
        for (int k = 0; k < 5; k++){
            lmkD[idx*10 + 2*k]     = (lp[(b*10 + 2*k)*HW + hw]     + (float)gx) * st;
            lmkD[idx*10 + 2*k + 1] = (lp[(b*10 + 2*k + 1)*HW + hw] + (float)gy) * st;
        }

        mcnt[idx] = 0; mfirst[idx] = 0x7fffffff; mpiou[idx] = 0.f;

        ax = ((float)gx + 0.5f) * st; ay = ((float)gy + 0.5f) * st;
        r = 2.5f * st;
        for (int g = 0; g < NG; g++){
            if (!__ballot(!f)) break;    // whole wave fg -> done (f monotone)
            if (!sval[g]) continue;
            float4 gv = sgb[g];
            bool inb = fminf(fminf(ax-gv.x, gv.z-ax), fminf(ay-gv.y, gv.w-ay)) > 0.f;
            float cx = (gv.x+gv.z)*0.5f, cy = (gv.y+gv.w)*0.5f;
            bool inc = fminf(fminf(ax-(cx-r), (cx+r)-ax), fminf(ay-(cy-r), (cy+r)-ay)) > 0.f;
            f = f || inb || inc;
        }
    }

    // single block-level atomic; wave offsets reconstructed from LDS prefix
    unsigned long long m = __ballot(f);
    int wave = tid >> 6, lane = tid & 63;
    if (lane == 0) swc[wave] = __popcll(m);
    __syncthreads();
    if (tid == 0){
        int tot = swc[0] + swc[1] + swc[2] + swc[3];
        sbase = tot ? atomicAdd(&ctr[CTR_FG(b)], tot) : 0;
    }
    __syncthreads();
    if (f){
        int wbase = sbase;
        for (int w = 0; w < 4; w++) if (w < wave) wbase += swc[w];
        int pos = wbase + __popcll(m & ((1ull << lane) - 1ull));
        fgList[b*NA + pos] = a;
        boxC[b*NA + pos] = bx;
        metaC[b*NA + pos] = make_float4(ax, ay, r, abv);
        ccPC[b*NA + pos] = ccPv;
        ccNC[b*NA + pos] = ccNv;
    }

    // block reduction of dense obj loss (no extra global loads)
    sred[tid] = so;
    for (int off = 128; off >= 1; off >>= 1){
        __syncthreads();
        if (tid < off) sred[tid] += sred[tid+off];
    }
    if (tid == 0) pObj[b*NCHUNK + blockIdx.x] = sred[0];
}

// ---------------- Kernel 2: per-(b,g) dyn_k top-k over compacted fg AoS; scatter matches --------
// (cost, idx) kept as one sortable u64: monotone-float-key(cost)<<32 | idx — u64 '<' == lex order.
__global__ void __launch_bounds__(SELT) k_select(
    const float4* __restrict__ boxes,
    const int* __restrict__ fgList, int* __restrict__ ctr,
    const float4* __restrict__ boxC, const float4* __restrict__ metaC,
    const float* __restrict__ ccPC, const float* __restrict__ ccNC,
    const float* __restrict__ gtb, const int* __restrict__ gtl, const unsigned char* __restrict__ gtv,
    int* __restrict__ mcnt, int* __restrict__ mfirst, float* __restrict__ mpiou,
    int* __restrict__ mList)
{
    int bg = blockIdx.x;
    int b = bg / NG, g = bg - b*NG;
    if (!gtv[b*NG+g]) return;      // uniform for the block; invalid GT matches nothing
    int tid = threadIdx.x;

    __shared__ float sIou[SELT*LP];
    __shared__ unsigned long long sK[SELT*LP];
    __shared__ int sDk;

    const float* gp = &gtb[(size_t)(b*NG+g)*4];
    float4 gb = make_float4(gp[0], gp[1], gp[2], gp[3]);
    bool lab0 = (gtl[b*NG+g] == 0);
    int nf = ctr[CTR_FG(b)];

    // hoisted GT-derived terms
    float ag = (gb.z - gb.x) * (gb.w - gb.y);
    float cx = (gb.x + gb.z) * 0.5f, cy = (gb.y + gb.w) * 0.5f;

    const float4* bC = boxC  + (size_t)b*NA;
    const float4* mC = metaC + (size_t)b*NA;
    const float*  cS = (lab0 ? ccPC : ccNC) + (size_t)b*NA;
    const int*    fL = fgList + (size_t)b*NA;

    // iou sentinel 0.f == reference's zero rows; key sentinel = all-ones (> any real key)
    float mi[TK]; unsigned long long mk[TK];
    #pragma unroll
    for (int k = 0; k < TK; k++){ mi[k] = 0.f; mk[k] = 0xFFFFFFFFFFFFFFFFull; }

    // manually software-pipelined scan: issue iteration i+1's loads before processing i
    int i = tid;
    float4 bxv, mt; float ccv; unsigned int ia;
    if (i < nf){ bxv = bC[i]; mt = mC[i]; ccv = cS[i]; ia = (unsigned int)fL[i]; }
    while (i < nf){
        int i2 = i + SELT;
        float4 bxv2, mt2; float ccv2; unsigned int ia2;
        if (i2 < nf){ bxv2 = bC[i2]; mt2 = mC[i2]; ccv2 = cS[i2]; ia2 = (unsigned int)fL[i2]; }
        // iou
        float tlx = fmaxf(gb.x, bxv.x), tly = fmaxf(gb.y, bxv.y);
        float brx = fminf(gb.z, bxv.z), bry = fminf(gb.w, bxv.w);
        float iw = fmaxf(brx - tlx, 0.f), ih = fmaxf(bry - tly, 0.f);
        float inter = iw * ih;
        float im = inter / (ag + mt.w - inter + 1e-8f);
        // center tests (anchor geometry precomputed)
        float ax = mt.x, ay = mt.y, r = mt.z;
        bool inb = fminf(fminf(ax-gb.x, gb.z-ax), fminf(ay-gb.y, gb.w-ay)) > 0.f;
        bool inc = fminf(fminf(ax-(cx-r), (cx+r)-ax), fminf(ay-(cy-r), (cy+r)-ay)) > 0.f;
        float c = ccv - 3.f * logf(im + 1e-8f);
        if (!(inb && inc)) c += 1e5f;
        // insert iou (descending)
        if (im > mi[TK-1]){
            float v = im;
            #pragma unroll
            for (int k = 0; k < TK; k++){
                if (v > mi[k]){ float t = mi[k]; mi[k] = v; v = t; }
            }
        }
        // insert packed (cost, idx) ascending
        unsigned int fb = __float_as_uint(c);
        unsigned int ck = fb ^ ((unsigned int)((int)fb >> 31) | 0x80000000u);
        unsigned long long key = ((unsigned long long)ck << 32) | ia;
        if (key < mk[TK-1]){
            unsigned long long kv = key;
            #pragma unroll
            for (int k = 0; k < TK; k++){
                if (kv < mk[k]){ unsigned long long t = mk[k]; mk[k] = kv; kv = t; }
            }
        }
        i = i2; bxv = bxv2; mt = mt2; ccv = ccv2; ia = ia2;
    }

    #pragma unroll
    for (int k = 0; k < TK; k++){
        sIou[tid*LP+k] = mi[k];
        sK[tid*LP+k] = mk[k];
    }

    for (int off = SELT/2; off >= 1; off >>= 1){
        __syncthreads();
        if (tid < off){
            { // merge descending iou lists
                float* Al = &sIou[tid*LP]; float* Bl = &sIou[(tid+off)*LP];
                float r2[TK]; int ii = 0, jj = 0;
                for (int k = 0; k < TK; k++){
                    bool ta = (jj >= TK) || (ii < TK && Al[ii] >= Bl[jj]);
                    r2[k] = ta ? Al[ii++] : Bl[jj++];
                }
                for (int k = 0; k < TK; k++) Al[k] = r2[k];
            }
            { // merge ascending u64 key lists
                unsigned long long* Ak = &sK[tid*LP]; unsigned long long* Bk = &sK[(tid+off)*LP];
                unsigned long long rk[TK]; int ii = 0, jj = 0;
                for (int k = 0; k < TK; k++){
                    bool ta = (jj >= TK) || (ii < TK && Ak[ii] <= Bk[jj]);
                    rk[k] = ta ? Ak[ii++] : Bk[jj++];
                }
                for (int k = 0; k < TK; k++) Ak[k] = rk[k];
            }
        }
    }
    __syncthreads();
    if (tid == 0){
        float s = 0.f;
        for (int k = 0; k < TK; k++) s += sIou[k];
        int dk = (int)s;
        if (dk < 1) dk = 1;
        if (dk > TK) dk = TK;
        sDk = dk;
    }
    __syncthreads();
    int dk = sDk;
    // matched set = first dk entries of the sorted key list
    if (tid < dk){
        unsigned long long kk = sK[tid];
        unsigned int a = (unsigned int)(kk & 0xFFFFFFFFull);
        if (a < (unsigned int)NA){      // skip sentinels when nf < dk
            int idx = b*NA + (int)a;
            int old = atomicAdd(&mcnt[idx], 1);
            if (old == 0){              // first match appends anchor to compact matched list
                int p = atomicAdd(&ctr[CTR_M(b)], 1);
                mList[b*MCAP + p] = (int)a;
            }
            atomicMin(&mfirst[idx], g);
            float4 bxv = boxes[idx];
            float tlx = fmaxf(gb.x, bxv.x), tly = fmaxf(gb.y, bxv.y);
            float brx = fminf(gb.z, bxv.z), bry = fminf(gb.w, bxv.w);
            float iw = fmaxf(brx - tlx, 0.f), ih = fmaxf(bry - tly, 0.f);
            float inter = iw * ih;
            float ab = (bxv.z - bxv.x) * (bxv.w - bxv.y);
            float im = inter / (ag + ab - inter + 1e-8f);
            atomicAdd(&mpiou[idx], im);   // single contributor when cnt==1 (only case it's read)
        }
    }
}

// ---------------- Kernel 3: fg-only losses + fused final combine -------------------------------
__global__ void __launch_bounds__(256) k_fg_loss(
    const float4* __restrict__ boxes, const float* __restrict__ objL, const float* __restrict__ clsL,
    const float* __restrict__ lmkD, const float* __restrict__ ccP, const float* __restrict__ ccN,
    const int* __restrict__ mcnt, const int* __restrict__ mfirst, const float* __restrict__ mpiou,
    const int* __restrict__ mList, int* __restrict__ ctr,
    const float* __restrict__ gtb, const float* __restrict__ gtlm, const int* __restrict__ gtl,
    const unsigned char* __restrict__ gtv, double* __restrict__ partials,
    const double* __restrict__ pObj, float* __restrict__ out)
{
    __shared__ float4 sgb[NG];
    __shared__ int slab[NG];
    __shared__ unsigned char sval[NG];
    __shared__ float slmk[NG*10];
    int b = blockIdx.y;
    int tid = threadIdx.x;
    if (tid < NG){
        const float* gp = &gtb[(size_t)(b*NG+tid)*4];
        sgb[tid] = make_float4(gp[0], gp[1], gp[2], gp[3]);
        slab[tid] = gtl[b*NG+tid];
        sval[tid] = gtv[b*NG+tid];
    }
    for (int i = tid; i < NG*10; i += 256) slmk[i] = gtlm[(size_t)b*NG*10 + i];
    __syncthreads();

    int n = ctr[CTR_M(b)];
    double lo = 0, lc = 0, li = 0, lnum = 0, lden = 0, nfg = 0;

    for (int i = blockIdx.x*256 + tid; i < n; i += FGB*256){
        int a = mList[b*MCAP + i];
        int idx = b*NA + a;
        int cnt = mcnt[idx];
        float4 bx = boxes[idx];
        float pious; int m;
        if (cnt == 1){ m = mfirst[idx]; pious = mpiou[idx]; }
        else {
            // conflict: argmin cost over ALL GTs (reference's keep = argmin, first-min on ties)
            int lvl, hw, gx, gy; float st;
            anchor_geom(a, lvl, hw, gx, gy, st);
            float ax = ((float)gx + 0.5f) * st, ay = ((float)gy + 0.5f) * st, r = 2.5f * st;
            float cp = ccP[idx], cn = ccN[idx];
            float ab = (bx.z - bx.x) * (bx.w - bx.y);
            float bestC = INFINITY, bestIou = 0.f; int bestG = 0;
            for (int g = 0; g < NG; g++){
                float4 gbv = sgb[g];
                int valid = sval[g];
                float tlx = fmaxf(gbv.x, bx.x), tly = fmaxf(gbv.y, bx.y);
                float brx = fminf(gbv.z, bx.z), bry = fminf(gbv.w, bx.w);
                float iw = fmaxf(brx - tlx, 0.f), ih = fmaxf(bry - tly, 0.f);
                float inter = iw * ih;
                float agv = (gbv.z - gbv.x) * (gbv.w - gbv.y);
                float im = inter / (agv + ab - inter + 1e-8f);
                bool inb = (fminf(fminf(ax-gbv.x, gbv.z-ax), fminf(ay-gbv.y, gbv.w-ay)) > 0.f) && valid;
                float cxg = (gbv.x + gbv.z) * 0.5f, cyg = (gbv.y + gbv.w) * 0.5f;
                bool inc = (fminf(fminf(ax-(cxg-r), (cxg+r)-ax), fminf(ay-(cyg-r), (cyg+r)-ay)) > 0.f) && valid;
                float cc = (slab[g] == 0) ? cp : cn;
                float c = cc - 3.f * logf(im + 1e-8f);
                if (!(inb && inc)) c += 1e5f;
                if (!valid) c += 1e9f;
                if (c < bestC){ bestC = c; bestG = g; bestIou = im; }
            }
            m = bestG; pious = bestIou;
        }
        lo += (double)(-objL[idx]);              // bce(x,1) - bce(x,0) = -x  (fg correction)
        float tgt = (slab[m] == 0) ? pious : 0.f;
        lc += (double)bce_(clsL[idx], tgt);
        li += (double)(1.f - giou_(bx, sgb[m]));
        #pragma unroll
        for (int k = 0; k < 5; k++){
            float tx = slmk[m*10 + 2*k];
            float ty = slmk[m*10 + 2*k + 1];
            if (tx >= 0.f && ty >= 0.f){
                lnum += (double)(sl1_(lmkD[idx*10 + 2*k] - tx) + sl1_(lmkD[idx*10 + 2*k + 1] - ty));
                lden += 1.0;
            }
        }
        nfg += 1.0;
    }

    __shared__ double s[6*256];
    s[0*256+tid] = lo; s[1*256+tid] = lc; s[2*256+tid] = li;
    s[3*256+tid] = lnum; s[4*256+tid] = lden; s[5*256+tid] = nfg;
    for (int off = 128; off >= 1; off >>= 1){
        __syncthreads();
        if (tid < off){
            #pragma unroll
            for (int q = 0; q < 6; q++) s[q*256+tid] += s[q*256+tid+off];
        }
    }
    if (tid == 0){
        #pragma unroll
        for (int q = 0; q < 6; q++) partials[(b*FGB + blockIdx.x)*6 + q] = s[q*256];
    }

    // ---- fused final combine: last block to finish does the reduction ----
    __threadfence();
    __shared__ int sLast;
    if (tid == 0) sLast = (atomicAdd(&ctr[CTR_DONE], 1) == NB*FGB - 1);
    __syncthreads();
    if (!sLast) return;

    __shared__ double sf[NB][5];   // lo, lc, li, ll, nfg per image
    if (tid < NB){
        double flo = 0, flc = 0, fli = 0, fln = 0, fld = 0, fnf = 0;
        for (int ch = 0; ch < NCHUNK; ch++) flo += pObj[tid*NCHUNK + ch];
        for (int blk = 0; blk < FGB; blk++){
            const double* p = &partials[(tid*FGB + blk)*6];
            flo += p[0]; flc += p[1]; fli += p[2];
            fln += p[3]; fld += p[4]; fnf += p[5];
        }
        sf[tid][0] = flo; sf[tid][1] = flc; sf[tid][2] = fli;
        sf[tid][3] = fln / fmax(fld, 1.0); sf[tid][4] = fnf;
    }
    __syncthreads();
    if (tid == 0){
        double flo = 0, flc = 0, fli = 0, fll = 0, fnfg = 0;
        for (int bb = 0; bb < NB; bb++){
            flo += sf[bb][0]; flc += sf[bb][1]; fli += sf[bb][2]; fll += sf[bb][3]; fnfg += sf[bb][4];
        }
        double nf2 = fmax(fnfg, 1.0);
        double liou = 5.0 * fli / nf2;
        double lobj = 1.0 * flo / nf2;
        double lcls = 1.0 * flc / nf2;
        double llmk = 5.0 * fll / nf2;
        out[0] = (float)(liou + lobj + lcls + llmk);
        out[1] = (float)liou;
        out[2] = (float)lobj;
        out[3] = (float)lcls;
        out[4] = (float)llmk;
    }
}

extern "C" void kernel_launch(void* const* d_in, const int* in_sizes, int n_in,
                              void* d_out, int out_size, void* d_ws, size_t ws_size,
                              hipStream_t stream) {
    const float* cls0 = (const float*)d_in[0];
    const float* reg0 = (const float*)d_in[1];
    const float* obj0 = (const float*)d_in[2];
    const float* lmk0 = (const float*)d_in[3];
    const float* cls1 = (const float*)d_in[4];
    const float* reg1 = (const float*)d_in[5];
    const float* obj1 = (const float*)d_in[6];
    const float* lmk1 = (const float*)d_in[7];
    const float* cls2 = (const float*)d_in[8];
    const float* reg2 = (const float*)d_in[9];
    const float* obj2 = (const float*)d_in[10];
    const float* lmk2 = (const float*)d_in[11];
    const float* gtb  = (const float*)d_in[12];
    const float* gtlm = (const float*)d_in[13];
    const int*   gtl  = (const int*)d_in[14];
    const unsigned char* gtv_raw = (const unsigned char*)d_in[15];
    float* out = (float*)d_out;

    char* ws = (char*)d_ws;
    size_t off = 0;
    float4* boxes = (float4*)(ws + off); off += (size_t)NB*NA*sizeof(float4);
    float4* boxC  = (float4*)(ws + off); off += (size_t)NB*NA*sizeof(float4);
    float4* metaC = (float4*)(ws + off); off += (size_t)NB*NA*sizeof(float4);
    float* lmkD = (float*)(ws + off); off += (size_t)NB*NA*10*sizeof(float);
    float* objL = (float*)(ws + off); off += (size_t)NB*NA*sizeof(float);
    float* clsL = (float*)(ws + off); off += (size_t)NB*NA*sizeof(float);
    float* ccP  = (float*)(ws + off); off += (size_t)NB*NA*sizeof(float);
    float* ccN  = (float*)(ws + off); off += (size_t)NB*NA*sizeof(float);
    float* ccPC = (float*)(ws + off); off += (size_t)NB*NA*sizeof(float);
    float* ccNC = (float*)(ws + off); off += (size_t)NB*NA*sizeof(float);
    float* mpiou = (float*)(ws + off); off += (size_t)NB*NA*sizeof(float);
    int* mcnt   = (int*)(ws + off);   off += (size_t)NB*NA*sizeof(int);
    int* mfirst = (int*)(ws + off);   off += (size_t)NB*NA*sizeof(int);
    int* fgList = (int*)(ws + off);   off += (size_t)NB*NA*sizeof(int);
    int* mList  = (int*)(ws + off);   off += (size_t)NB*MCAP*sizeof(int);
    int* ctr    = (int*)(ws + off);   off += (size_t)8192;   // padded: nFg/nM per-line + done
    double* pObj = (double*)(ws + off); off += (size_t)NB*NCHUNK*sizeof(double);
    double* partials = (double*)(ws + off); off += (size_t)NB*FGB*6*sizeof(double);
    unsigned char* gtv = (unsigned char*)(ws + off); off += (size_t)NB*NG;

    hipMemsetAsync(ctr, 0, 8192, stream);

    dim3 grdA(NCHUNK, NB);
    k_decode<<<grdA, dim3(256), 0, stream>>>(cls0, reg0, obj0, lmk0, cls1, reg1, obj1, lmk1,
                                             cls2, reg2, obj2, lmk2, gtb, gtv_raw, gtv,
                                             boxes, objL, clsL, lmkD, ccP, ccN,
                                             fgList, ctr, boxC, metaC, ccPC, ccNC,
                                             mcnt, mfirst, mpiou, pObj);

    k_select<<<dim3(NB*NG), dim3(SELT), 0, stream>>>(boxes, fgList, ctr, boxC, metaC, ccPC, ccNC,
                                                     gtb, gtl, gtv, mcnt, mfirst, mpiou, mList);

    k_fg_loss<<<dim3(FGB, NB), dim3(256), 0, stream>>>(boxes, objL, clsL, lmkD, ccP, ccN,
                                                       mcnt, mfirst, mpiou, mList, ctr,
                                                       gtb, gtlm, gtl, gtv, partials,
                                                       pObj, out);
}